// Round 1
// baseline (2767.751 us; speedup 1.0000x reference)
//
#include <hip/hip_runtime.h>

typedef __attribute__((ext_vector_type(4))) float v4f;
typedef __attribute__((ext_vector_type(4))) float f32x4;
typedef __attribute__((ext_vector_type(8))) __bf16 bf16x8;
typedef __attribute__((ext_vector_type(4))) unsigned short v4u16;

__device__ __forceinline__ unsigned short f2bf(float f) {
    union { float f; unsigned u; } v; v.f = f;
    unsigned r = v.u + 0x7fffu + ((v.u >> 16) & 1u);
    return (unsigned short)(r >> 16);
}

#define GLDS16(gp, lp) __builtin_amdgcn_global_load_lds( \
    (const __attribute__((address_space(1))) void*)(gp), \
    (__attribute__((address_space(3))) void*)(lp), 16, 0, 0)

// ---------------------------------------------------------------------------
// GEMM: C[M][N] (fp32) = A[M][K] (bf16) * Bt[N][K]^T (bf16).  128x128 tile,
// BK=32, 4 waves (2x2), 4x4 frags of mfma_f32_16x16x32_bf16 per wave.
// ---------------------------------------------------------------------------
__global__ __launch_bounds__(256) void gemm_bf16(
    const unsigned short* __restrict__ A,
    const unsigned short* __restrict__ Bt,
    float* __restrict__ C,
    int M, int N, int K)
{
    __shared__ __align__(16) unsigned short lA[4096];
    __shared__ __align__(16) unsigned short lB[4096];
    const int tid  = threadIdx.x;
    const int wave = tid >> 6;
    const int lane = tid & 63;
    const int wr = wave >> 1, wc = wave & 1;
    const long m0 = (long)blockIdx.x * 128, n0 = (long)blockIdx.y * 128;

    // staging: element e = issue*2048 + tid*8 ; tile row = e/32, col = e%32
    const int srow = tid >> 2;
    const int scol = (tid & 3) * 8;
    const unsigned short* gA0 = A  + (m0 + srow) * (long)K + scol;
    const unsigned short* gB0 = Bt + (n0 + srow) * (long)K + scol;
    const long rstride = 64l * K;                    // +64 tile rows
    unsigned short* lA0 = lA + wave * 512;           // wave-uniform LDS base
    unsigned short* lB0 = lB + wave * 512;

    const int fr = lane & 15;
    const int kg = (lane >> 4) * 8;
    const int arow = (wr * 64 + fr) * 32 + kg;
    const int brow = (wc * 64 + fr) * 32 + kg;

    f32x4 acc[4][4] = {};

    for (int k0 = 0; k0 < K; k0 += 32) {
        __syncthreads();
        GLDS16(gA0 + k0,           lA0);
        GLDS16(gA0 + k0 + rstride, lA0 + 2048);
        GLDS16(gB0 + k0,           lB0);
        GLDS16(gB0 + k0 + rstride, lB0 + 2048);
        __syncthreads();
        bf16x8 af[4], bb[4];
#pragma unroll
        for (int m = 0; m < 4; ++m)
            af[m] = *(const bf16x8*)(lA + arow + m * 512);
#pragma unroll
        for (int n = 0; n < 4; ++n)
            bb[n] = *(const bf16x8*)(lB + brow + n * 512);
#pragma unroll
        for (int m = 0; m < 4; ++m)
#pragma unroll
            for (int n = 0; n < 4; ++n)
                acc[m][n] = __builtin_amdgcn_mfma_f32_16x16x32_bf16(
                    af[m], bb[n], acc[m][n], 0, 0, 0);
    }

    float* Cbase = C + (m0 + wr * 64 + (lane >> 4) * 4) * (long)N
                     + n0 + wc * 64 + fr;
#pragma unroll
    for (int m = 0; m < 4; ++m)
#pragma unroll
        for (int n = 0; n < 4; ++n) {
            float* cp = Cbase + m * 16 * (long)N + n * 16;
#pragma unroll
            for (int r = 0; r < 4; ++r)
                cp[r * (long)N] = acc[m][n][r];
        }
}

// ---------------------------------------------------------------------------
// Weight prep: transpose [K][N] fp32 -> [N][K] bf16 (64x64 LDS tiles)
// ---------------------------------------------------------------------------
__global__ __launch_bounds__(256) void transW(
    const float* __restrict__ in, unsigned short* __restrict__ outp,
    int K, int N, long inl, long outl)
{
    __shared__ unsigned short tile[64][65];
    const float* ip = in + (long)blockIdx.z * inl;
    unsigned short* op = outp + (long)blockIdx.z * outl;
    int n0 = blockIdx.x * 64, k0 = blockIdx.y * 64;
    int cc = threadIdx.x & 63, rr = threadIdx.x >> 6;
#pragma unroll
    for (int i = 0; i < 16; ++i) {
        int r = i * 4 + rr;
        tile[r][cc] = f2bf(ip[(long)(k0 + r) * N + n0 + cc]);
    }
    __syncthreads();
#pragma unroll
    for (int i = 0; i < 16; ++i) {
        int r = i * 4 + rr;
        op[(long)(n0 + r) * K + k0 + cc] = tile[cc][r];
    }
}

// x_in -> x (fp32 residual) + xb (bf16)
__global__ __launch_bounds__(256) void init_x(
    const float* __restrict__ xin, float* __restrict__ x,
    unsigned short* __restrict__ xb)
{
    long i = ((long)blockIdx.x * 256 + threadIdx.x) * 4;
    v4f v = *(const v4f*)(xin + i);
    *(v4f*)(x + i) = v;
    v4u16 pk;
#pragma unroll
    for (int j = 0; j < 4; ++j) pk[j] = f2bf(v[j]);
    *(v4u16*)(xb + i) = pk;
}

// ---------------------------------------------------------------------------
// depthwise causal conv(width 4) + bias + silu : proj[:, :2048] -> u (fp32)
// ---------------------------------------------------------------------------
__global__ __launch_bounds__(256) void conv_silu(
    const float* __restrict__ proj, const float* __restrict__ cw,
    const float* __restrict__ cb, float* __restrict__ u)
{
    long gid = (long)blockIdx.x * 256 + threadIdx.x;
    int r = (int)(gid >> 9);
    int d = ((int)gid & 511) * 4;
    int t = r & 2047;
    v4f xs[4];
#pragma unroll
    for (int k = 0; k < 4; ++k) {
        int tr = t - 3 + k;
        if (tr >= 0) xs[k] = *(const v4f*)(proj + (long)(r - 3 + k) * 2176 + d);
        else         xs[k] = (v4f){0.f, 0.f, 0.f, 0.f};
    }
    v4f ov;
#pragma unroll
    for (int i = 0; i < 4; ++i) {
        v4f w = *(const v4f*)(cw + (long)(d + i) * 4);
        float a = xs[0][i]*w[0] + xs[1][i]*w[1] + xs[2][i]*w[2] + xs[3][i]*w[3]
                  + cb[d + i];
        ov[i] = a / (1.f + __expf(-a));
    }
    *(v4f*)(u + (long)r * 2048 + d) = ov;
}

// ---------------------------------------------------------------------------
// G[r][k] = (-0.5)^k * dot64(C_r, B_{r-k}),  k = 0..min(31, t); else 0
// one wave per row r
// ---------------------------------------------------------------------------
__global__ __launch_bounds__(256) void gker(
    const float* __restrict__ proj, float* __restrict__ G)
{
    int r = blockIdx.x * 4 + (threadIdx.x >> 6);
    int lane = threadIdx.x & 63;
    int t = r & 2047;
    float c = proj[(long)r * 2176 + 2112 + lane];
    float myg = 0.f;
    int kmax = t < 31 ? t : 31;
    for (int k = 0; k <= kmax; ++k) {
        float bv = proj[(long)(r - k) * 2176 + 2048 + lane];
        float p = c * bv;
#pragma unroll
        for (int m = 32; m >= 1; m >>= 1) p += __shfl_xor(p, m, 64);
        if (lane == k) myg = p;
    }
    if (lane < 32) {
        float s = ((lane & 1) ? -1.f : 1.f) * exp2f(-(float)lane);
        G[(long)r * 32 + lane] = myg * s;
    }
}

// ---------------------------------------------------------------------------
// banded: y[r][d] = sum_k G[r][k] * u[r-k][d]  -> yb (bf16)
// block: 16 rows x 64 cols
// ---------------------------------------------------------------------------
__global__ __launch_bounds__(256) void banded(
    const float* __restrict__ G, const float* __restrict__ u,
    unsigned short* __restrict__ yb)
{
    int r = blockIdx.x * 16 + (threadIdx.x >> 4);
    int d = blockIdx.y * 64 + (threadIdx.x & 15) * 4;
    const float* grow = G + (long)r * 32;
    v4f acc = (v4f){0.f, 0.f, 0.f, 0.f};
    for (int k = 0; k < 32; ++k) {
        int rc = r - k; if (rc < 0) rc = 0;
        v4f uv = *(const v4f*)(u + (long)rc * 2048 + d);
        acc += grow[k] * uv;   // G==0 when k exceeds causal range
    }
    v4u16 pk;
#pragma unroll
    for (int j = 0; j < 4; ++j) pk[j] = f2bf(acc[j]);
    *(v4u16*)(yb + (long)r * 2048 + d) = pk;
}

// ---------------------------------------------------------------------------
// LayerNorm(tmp + xres) * g + b -> xout (fp32) and xbout (bf16)
// one block (256 thr) per row of 1024
// ---------------------------------------------------------------------------
__global__ __launch_bounds__(256) void ln_fuse(
    const float* __restrict__ tmp, const float* __restrict__ xres,
    const float* __restrict__ g, const float* __restrict__ b,
    float* __restrict__ xout, unsigned short* __restrict__ xbout)
{
    int row = blockIdx.x;
    int tid = threadIdx.x;
    v4f tv = *(const v4f*)(tmp  + (long)row * 1024 + tid * 4);
    v4f rv = *(const v4f*)(xres + (long)row * 1024 + tid * 4);
    v4f v = tv + rv;
    float s = v[0] + v[1] + v[2] + v[3];
    float q = v[0]*v[0] + v[1]*v[1] + v[2]*v[2] + v[3]*v[3];
#pragma unroll
    for (int m = 32; m >= 1; m >>= 1) {
        s += __shfl_xor(s, m, 64);
        q += __shfl_xor(q, m, 64);
    }
    __shared__ float ls[4], lq[4];
    int wave = tid >> 6, lane = tid & 63;
    if (lane == 0) { ls[wave] = s; lq[wave] = q; }
    __syncthreads();
    s = ls[0] + ls[1] + ls[2] + ls[3];
    q = lq[0] + lq[1] + lq[2] + lq[3];
    float mean = s * (1.f / 1024.f);
    float var  = q * (1.f / 1024.f) - mean * mean;
    float rstd = rsqrtf(var + 1e-5f);
    v4f gv = *(const v4f*)(g + tid * 4);
    v4f bv = *(const v4f*)(b + tid * 4);
    v4f o;
#pragma unroll
    for (int i = 0; i < 4; ++i) o[i] = (v[i] - mean) * rstd * gv[i] + bv[i];
    *(v4f*)(xout + (long)row * 1024 + tid * 4) = o;
    v4u16 pk;
#pragma unroll
    for (int i = 0; i < 4; ++i) pk[i] = f2bf(o[i]);
    *(v4u16*)(xbout + (long)row * 1024 + tid * 4) = pk;
}

// ---------------------------------------------------------------------------
// attention core: one lane = one q row. qkv[r][0:1024)=q, [1024:2048)=k,
// [2048:3072)=v. Unnormalized softmax (scores bounded, fp32-safe). -> ob bf16
// ---------------------------------------------------------------------------
__global__ __launch_bounds__(64) void attn_core(
    const float* __restrict__ qkv, unsigned short* __restrict__ ob)
{
    int bh = blockIdx.x;
    int b = bh >> 4, h = bh & 15;
    int qc = blockIdx.y;
    int lane = threadIdx.x;
    int q = qc * 64 + lane;
    long rowb = (long)b * 2048;
    const float* qp = qkv + (rowb + q) * 3072 + h * 64;
    v4f qr[16];
#pragma unroll
    for (int j = 0; j < 16; ++j) qr[j] = *(const v4f*)(qp + j * 4);
    v4f o[16];
#pragma unroll
    for (int j = 0; j < 16; ++j) o[j] = (v4f){0.f, 0.f, 0.f, 0.f};
    float denom = 0.f;
    const float* kb = qkv + rowb * 3072 + 1024 + h * 64;
    const float* vb = qkv + rowb * 3072 + 2048 + h * 64;
    int tmax = qc * 64 + 63;
    for (int t = 0; t <= tmax; ++t) {
        const float* kp = kb + (long)t * 3072;
        v4f sv = (v4f){0.f, 0.f, 0.f, 0.f};
#pragma unroll
        for (int j = 0; j < 16; ++j) sv += qr[j] * *(const v4f*)(kp + j * 4);
        float sdot = (sv[0] + sv[1]) + (sv[2] + sv[3]);
        float p = (t <= q) ? __expf(sdot * 0.125f) : 0.f;
        denom += p;
        const float* vp = vb + (long)t * 3072;
#pragma unroll
        for (int j = 0; j < 16; ++j) o[j] += p * *(const v4f*)(vp + j * 4);
    }
    float inv = 1.f / denom;
    unsigned short* op = ob + (rowb + q) * 1024 + h * 64;
#pragma unroll
    for (int j = 0; j < 16; ++j) {
        v4f t4 = o[j] * inv;
        v4u16 pk;
#pragma unroll
        for (int i = 0; i < 4; ++i) pk[i] = f2bf(t4[i]);
        *(v4u16*)(op + j * 4) = pk;
    }
}

// ---------------------------------------------------------------------------
extern "C" void kernel_launch(void* const* d_in, const int* in_sizes, int n_in,
                              void* d_out, int out_size, void* d_ws, size_t ws_size,
                              hipStream_t stream) {
    const float* x_in = (const float*)d_in[0];
    const float* Wi   = (const float*)d_in[1];
    const float* cw   = (const float*)d_in[2];
    const float* cb   = (const float*)d_in[3];
    const float* Wo   = (const float*)d_in[4];
    const float* lng  = (const float*)d_in[5];
    const float* lnb  = (const float*)d_in[6];
    const float* wq   = (const float*)d_in[7];
    const float* wk   = (const float*)d_in[8];
    const float* wv   = (const float*)d_in[9];
    const float* wo   = (const float*)d_in[10];
    const float* alng = (const float*)d_in[11];
    const float* alnb = (const float*)d_in[12];
    float* out = (float*)d_out;

    char* ws = (char*)d_ws;
    size_t off = 0;
    auto alloc = [&](size_t bytes) -> void* {
        void* p = ws + off; off += (bytes + 255) & ~(size_t)255; return p;
    };
    unsigned short* xb    = (unsigned short*)alloc(4096ull * 1024 * 2);
    float*          x     = (float*)         alloc(4096ull * 1024 * 4);
    float*          proj  = (float*)         alloc(4096ull * 3072 * 4); // also qkv
    float*          u     = (float*)         alloc(4096ull * 2048 * 4);
    float*          G     = (float*)         alloc(4096ull * 32 * 4);
    unsigned short* yb    = (unsigned short*)alloc(4096ull * 2048 * 2); // also ob
    float*          tmp   = (float*)         alloc(4096ull * 1024 * 4);
    unsigned short* WiT   = (unsigned short*)alloc(5ull * 2176 * 1024 * 2);
    unsigned short* WoT   = (unsigned short*)alloc(5ull * 1024 * 2048 * 2);
    unsigned short* WqkvT = (unsigned short*)alloc(3072ull * 1024 * 2);
    unsigned short* WoaT  = (unsigned short*)alloc(1024ull * 1024 * 2);

    // ---- weight prep ----
    transW<<<dim3(34, 16, 5), 256, 0, stream>>>(Wi, WiT, 1024, 2176,
        1024l * 2176, 2176l * 1024);
    transW<<<dim3(16, 32, 5), 256, 0, stream>>>(Wo, WoT, 2048, 1024,
        2048l * 1024, 1024l * 2048);
    transW<<<dim3(16, 16, 1), 256, 0, stream>>>(wq, WqkvT,             1024, 1024, 0, 0);
    transW<<<dim3(16, 16, 1), 256, 0, stream>>>(wk, WqkvT + 1024l*1024,1024, 1024, 0, 0);
    transW<<<dim3(16, 16, 1), 256, 0, stream>>>(wv, WqkvT + 2048l*1024,1024, 1024, 0, 0);
    transW<<<dim3(16, 16, 1), 256, 0, stream>>>(wo, WoaT,              1024, 1024, 0, 0);

    init_x<<<4096, 256, 0, stream>>>(x_in, x, xb);

    // ---- 5 SSM layers ----
    for (int j = 0; j < 5; ++j) {
        gemm_bf16<<<dim3(32, 17), 256, 0, stream>>>(
            xb, WiT + (long)j * 2176 * 1024, proj, 4096, 2176, 1024);
        conv_silu<<<8192, 256, 0, stream>>>(
            proj, cw + (long)j * 2048 * 4, cb + (long)j * 2048, u);
        gker<<<1024, 256, 0, stream>>>(proj, G);
        banded<<<dim3(256, 32), 256, 0, stream>>>(G, u, yb);
        gemm_bf16<<<dim3(32, 8), 256, 0, stream>>>(
            yb, WoT + (long)j * 1024 * 2048, tmp, 4096, 1024, 2048);
        ln_fuse<<<4096, 256, 0, stream>>>(
            tmp, x, lng + j * 1024, lnb + j * 1024, x, xb);
    }

    // ---- attention layer ----
    gemm_bf16<<<dim3(32, 24), 256, 0, stream>>>(xb, WqkvT, proj, 4096, 3072, 1024);
    attn_core<<<dim3(32, 32), 64, 0, stream>>>(proj, yb);
    gemm_bf16<<<dim3(32, 8), 256, 0, stream>>>(yb, WoaT, tmp, 4096, 1024, 1024);
    ln_fuse<<<4096, 256, 0, stream>>>(tmp, x, alng, alnb, out, xb);
}

// Round 3
// 1240.199 us; speedup vs baseline: 2.2317x; 2.2317x over previous
//
#include <hip/hip_runtime.h>

typedef __attribute__((ext_vector_type(4))) float v4f;
typedef __attribute__((ext_vector_type(4))) float f32x4;
typedef __attribute__((ext_vector_type(8))) __bf16 bf16x8;
typedef __attribute__((ext_vector_type(4))) unsigned short v4u16;

__device__ __forceinline__ unsigned short f2bf(float f) {
    union { float f; unsigned u; } v; v.f = f;
    unsigned r = v.u + 0x7fffu + ((v.u >> 16) & 1u);
    return (unsigned short)(r >> 16);
}

#define GLDS16(gp, lp) __builtin_amdgcn_global_load_lds( \
    (const __attribute__((address_space(1))) void*)(gp), \
    (__attribute__((address_space(3))) void*)(lp), 16, 0, 0)

// ---------------------------------------------------------------------------
// GEMM: C[M][N] (fp32) = A[M][K] (bf16) * Bt[N][K]^T (bf16).  128x128 tile,
// BK=32, 4 waves (2x2), 4x4 frags of mfma_f32_16x16x32_bf16 per wave.
// ---------------------------------------------------------------------------
__global__ __launch_bounds__(256) void gemm_bf16(
    const unsigned short* __restrict__ A,
    const unsigned short* __restrict__ Bt,
    float* __restrict__ C,
    int M, int N, int K)
{
    __shared__ __align__(16) unsigned short lA[4096];
    __shared__ __align__(16) unsigned short lB[4096];
    const int tid  = threadIdx.x;
    const int wave = tid >> 6;
    const int lane = tid & 63;
    const int wr = wave >> 1, wc = wave & 1;
    const long m0 = (long)blockIdx.x * 128, n0 = (long)blockIdx.y * 128;

    const int srow = tid >> 2;
    const int scol = (tid & 3) * 8;
    const unsigned short* gA0 = A  + (m0 + srow) * (long)K + scol;
    const unsigned short* gB0 = Bt + (n0 + srow) * (long)K + scol;
    const long rstride = 64l * K;
    unsigned short* lA0 = lA + wave * 512;
    unsigned short* lB0 = lB + wave * 512;

    const int fr = lane & 15;
    const int kg = (lane >> 4) * 8;
    const int arow = (wr * 64 + fr) * 32 + kg;
    const int brow = (wc * 64 + fr) * 32 + kg;

    f32x4 acc[4][4] = {};

    for (int k0 = 0; k0 < K; k0 += 32) {
        __syncthreads();
        GLDS16(gA0 + k0,           lA0);
        GLDS16(gA0 + k0 + rstride, lA0 + 2048);
        GLDS16(gB0 + k0,           lB0);
        GLDS16(gB0 + k0 + rstride, lB0 + 2048);
        __syncthreads();
        bf16x8 af[4], bb[4];
#pragma unroll
        for (int m = 0; m < 4; ++m)
            af[m] = *(const bf16x8*)(lA + arow + m * 512);
#pragma unroll
        for (int n = 0; n < 4; ++n)
            bb[n] = *(const bf16x8*)(lB + brow + n * 512);
#pragma unroll
        for (int m = 0; m < 4; ++m)
#pragma unroll
            for (int n = 0; n < 4; ++n)
                acc[m][n] = __builtin_amdgcn_mfma_f32_16x16x32_bf16(
                    af[m], bb[n], acc[m][n], 0, 0, 0);
    }

    float* Cbase = C + (m0 + wr * 64 + (lane >> 4) * 4) * (long)N
                     + n0 + wc * 64 + fr;
#pragma unroll
    for (int m = 0; m < 4; ++m)
#pragma unroll
        for (int n = 0; n < 4; ++n) {
            float* cp = Cbase + m * 16 * (long)N + n * 16;
#pragma unroll
            for (int r = 0; r < 4; ++r)
                cp[r * (long)N] = acc[m][n][r];
        }
}

// ---------------------------------------------------------------------------
// Weight prep: transpose [K][N] fp32 -> [N][K] bf16 (64x64 LDS tiles)
// ---------------------------------------------------------------------------
__global__ __launch_bounds__(256) void transW(
    const float* __restrict__ in, unsigned short* __restrict__ outp,
    int K, int N, long inl, long outl)
{
    __shared__ unsigned short tile[64][65];
    const float* ip = in + (long)blockIdx.z * inl;
    unsigned short* op = outp + (long)blockIdx.z * outl;
    int n0 = blockIdx.x * 64, k0 = blockIdx.y * 64;
    int cc = threadIdx.x & 63, rr = threadIdx.x >> 6;
#pragma unroll
    for (int i = 0; i < 16; ++i) {
        int r = i * 4 + rr;
        tile[r][cc] = f2bf(ip[(long)(k0 + r) * N + n0 + cc]);
    }
    __syncthreads();
#pragma unroll
    for (int i = 0; i < 16; ++i) {
        int r = i * 4 + rr;
        op[(long)(n0 + r) * K + k0 + cc] = tile[cc][r];
    }
}

// x_in -> x (fp32 residual) + xb (bf16)
__global__ __launch_bounds__(256) void init_x(
    const float* __restrict__ xin, float* __restrict__ x,
    unsigned short* __restrict__ xb)
{
    long i = ((long)blockIdx.x * 256 + threadIdx.x) * 4;
    v4f v = *(const v4f*)(xin + i);
    *(v4f*)(x + i) = v;
    v4u16 pk;
#pragma unroll
    for (int j = 0; j < 4; ++j) pk[j] = f2bf(v[j]);
    *(v4u16*)(xb + i) = pk;
}

// ---------------------------------------------------------------------------
// depthwise causal conv(width 4) + bias + silu : proj[:, :2048] -> u (fp32)
// ---------------------------------------------------------------------------
__global__ __launch_bounds__(256) void conv_silu(
    const float* __restrict__ proj, const float* __restrict__ cw,
    const float* __restrict__ cb, float* __restrict__ u)
{
    long gid = (long)blockIdx.x * 256 + threadIdx.x;
    int r = (int)(gid >> 9);
    int d = ((int)gid & 511) * 4;
    int t = r & 2047;
    v4f xs[4];
#pragma unroll
    for (int k = 0; k < 4; ++k) {
        int tr = t - 3 + k;
        if (tr >= 0) xs[k] = *(const v4f*)(proj + (long)(r - 3 + k) * 2176 + d);
        else         xs[k] = (v4f){0.f, 0.f, 0.f, 0.f};
    }
    v4f ov;
#pragma unroll
    for (int i = 0; i < 4; ++i) {
        v4f w = *(const v4f*)(cw + (long)(d + i) * 4);
        float a = xs[0][i]*w[0] + xs[1][i]*w[1] + xs[2][i]*w[2] + xs[3][i]*w[3]
                  + cb[d + i];
        ov[i] = a / (1.f + __expf(-a));
    }
    *(v4f*)(u + (long)r * 2048 + d) = ov;
}

// ---------------------------------------------------------------------------
// G[r][k] = (-0.5)^k * dot64(C_r, B_{r-k}),  k = 0..min(31, t); else 0
// ---------------------------------------------------------------------------
__global__ __launch_bounds__(256) void gker(
    const float* __restrict__ proj, float* __restrict__ G)
{
    int r = blockIdx.x * 4 + (threadIdx.x >> 6);
    int lane = threadIdx.x & 63;
    int t = r & 2047;
    float c = proj[(long)r * 2176 + 2112 + lane];
    float myg = 0.f;
    int kmax = t < 31 ? t : 31;
    for (int k = 0; k <= kmax; ++k) {
        float bv = proj[(long)(r - k) * 2176 + 2048 + lane];
        float p = c * bv;
#pragma unroll
        for (int m = 32; m >= 1; m >>= 1) p += __shfl_xor(p, m, 64);
        if (lane == k) myg = p;
    }
    if (lane < 32) {
        float s = ((lane & 1) ? -1.f : 1.f) * exp2f(-(float)lane);
        G[(long)r * 32 + lane] = myg * s;
    }
}

// ---------------------------------------------------------------------------
// banded: y[r][d] = sum_k G[r][k] * u[r-k][d]  -> yb (bf16)
// ---------------------------------------------------------------------------
__global__ __launch_bounds__(256) void banded(
    const float* __restrict__ G, const float* __restrict__ u,
    unsigned short* __restrict__ yb)
{
    int r = blockIdx.x * 16 + (threadIdx.x >> 4);
    int d = blockIdx.y * 64 + (threadIdx.x & 15) * 4;
    const float* grow = G + (long)r * 32;
    v4f acc = (v4f){0.f, 0.f, 0.f, 0.f};
    for (int k = 0; k < 32; ++k) {
        int rc = r - k; if (rc < 0) rc = 0;
        v4f uv = *(const v4f*)(u + (long)rc * 2048 + d);
        acc += grow[k] * uv;
    }
    v4u16 pk;
#pragma unroll
    for (int j = 0; j < 4; ++j) pk[j] = f2bf(acc[j]);
    *(v4u16*)(yb + (long)r * 2048 + d) = pk;
}

// ---------------------------------------------------------------------------
// LayerNorm(tmp + xres) * g + b -> xout (fp32) and xbout (bf16)
// ---------------------------------------------------------------------------
__global__ __launch_bounds__(256) void ln_fuse(
    const float* __restrict__ tmp, const float* __restrict__ xres,
    const float* __restrict__ g, const float* __restrict__ b,
    float* __restrict__ xout, unsigned short* __restrict__ xbout)
{
    int row = blockIdx.x;
    int tid = threadIdx.x;
    v4f tv = *(const v4f*)(tmp  + (long)row * 1024 + tid * 4);
    v4f rv = *(const v4f*)(xres + (long)row * 1024 + tid * 4);
    v4f v = tv + rv;
    float s = v[0] + v[1] + v[2] + v[3];
    float q = v[0]*v[0] + v[1]*v[1] + v[2]*v[2] + v[3]*v[3];
#pragma unroll
    for (int m = 32; m >= 1; m >>= 1) {
        s += __shfl_xor(s, m, 64);
        q += __shfl_xor(q, m, 64);
    }
    __shared__ float ls[4], lq[4];
    int wave = tid >> 6, lane = tid & 63;
    if (lane == 0) { ls[wave] = s; lq[wave] = q; }
    __syncthreads();
    s = ls[0] + ls[1] + ls[2] + ls[3];
    q = lq[0] + lq[1] + lq[2] + lq[3];
    float mean = s * (1.f / 1024.f);
    float var  = q * (1.f / 1024.f) - mean * mean;
    float rstd = rsqrtf(var + 1e-5f);
    v4f gv = *(const v4f*)(g + tid * 4);
    v4f bv = *(const v4f*)(b + tid * 4);
    v4f o;
#pragma unroll
    for (int i = 0; i < 4; ++i) o[i] = (v[i] - mean) * rstd * gv[i] + bv[i];
    *(v4f*)(xout + (long)row * 1024 + tid * 4) = o;
    v4u16 pk;
#pragma unroll
    for (int i = 0; i < 4; ++i) pk[i] = f2bf(o[i]);
    *(v4u16*)(xbout + (long)row * 1024 + tid * 4) = pk;
}

// ---------------------------------------------------------------------------
// qkv split: proj [4096][3072] fp32 -> qkvb [3][32][2048][64] bf16
// (q segment pre-scaled by 1/8)
// ---------------------------------------------------------------------------
__global__ __launch_bounds__(256) void qkv_split(
    const float* __restrict__ proj, unsigned short* __restrict__ qkvb)
{
    long gid = (long)blockIdx.x * 256 + threadIdx.x;   // 4096*768
    long r = gid / 768;
    int cc4 = (int)(gid - r * 768);
    int c = cc4 * 4;
    int s = c >> 10;
    int ci = c & 1023;
    int h = ci >> 6, d = ci & 63;
    int b = (int)(r >> 11), t = (int)(r & 2047);
    v4f v = *(const v4f*)(proj + r * 3072 + c);
    float sc = (s == 0) ? 0.125f : 1.f;
    v4u16 pk;
#pragma unroll
    for (int j = 0; j < 4; ++j) pk[j] = f2bf(v[j] * sc);
    *(v4u16*)(qkvb + (((long)s * 32 + b * 16 + h) * 2048 + t) * 64 + d) = pk;
}

// ---------------------------------------------------------------------------
// MFMA flash attention. grid (bh=32, qt=32), 256 thr = 4 waves.
// Wave w owns q rows qt*64 + w*16 .. +16. KV blocks of 64.
// LDS: K [64t][64d] swizzled; V^T [64d][64t] swizzled; per-wave P [16][64].
// ---------------------------------------------------------------------------
__global__ __launch_bounds__(256) void attn_mfma(
    const unsigned short* __restrict__ qkvb,   // [3][32][2048][64]
    unsigned short* __restrict__ ob)           // [4096][1024]
{
    __shared__ __align__(16) unsigned short lK[4096];
    __shared__ __align__(16) unsigned short lV[4096];   // transposed [d][t]
    __shared__ __align__(16) unsigned short lP[4][1024];

    const int tid  = threadIdx.x;
    const int wave = tid >> 6;
    const int lane = tid & 63;
    const int bh = blockIdx.x;          // b*16+h
    const int qt = blockIdx.y;
    const long base = (long)bh * 2048 * 64;
    const unsigned short* Qg = qkvb + base;
    const unsigned short* Kg = qkvb + 32l * 2048 * 64 + base;
    const unsigned short* Vg = qkvb + 64l * 2048 * 64 + base;

    const int qr0  = qt * 64 + wave * 16;
    const int lrow = lane & 15;
    const int lgrp = lane >> 4;

    bf16x8 qf[2];
    {
        const unsigned short* qp = Qg + (long)(qr0 + lrow) * 64 + lgrp * 8;
        qf[0] = *(const bf16x8*)(qp);
        qf[1] = *(const bf16x8*)(qp + 32);
    }

    f32x4 oacc[4] = {};
    float m[4], l[4];
#pragma unroll
    for (int r = 0; r < 4; ++r) { m[r] = -1e30f; l[r] = 0.f; }

    unsigned short* Pw = lP[wave];
    const int srow = tid >> 2;           // staging row 0..63
    const int sq   = tid & 3;            // quarter of a row

    const int nkv = qt + 1;
    for (int kb = 0; kb < nkv; ++kb) {
        const int t0 = kb * 64;
        __syncthreads();
        // --- stage K (row-major, swizzled) ---
        {
            const unsigned short* kp = Kg + (long)(t0 + srow) * 64 + sq * 16;
            uint4 k0 = *(const uint4*)(kp);
            uint4 k1 = *(const uint4*)(kp + 8);
            int off = srow * 128 + sq * 32;
            int sw  = (srow & 7) << 4;
            *(uint4*)((char*)lK + ( off        ^ sw)) = k0;
            *(uint4*)((char*)lK + ((off + 16)  ^ sw)) = k1;
            // --- stage V transposed ---
            const unsigned short* vp = Vg + (long)(t0 + srow) * 64 + sq * 16;
            union { uint4 u4[2]; unsigned short us[16]; } vv;
            vv.u4[0] = *(const uint4*)(vp);
            vv.u4[1] = *(const uint4*)(vp + 8);
#pragma unroll
            for (int i = 0; i < 16; ++i) {
                int d = sq * 16 + i;
                int vo = (d * 128 + srow * 2) ^ ((d & 7) << 4);
                *(unsigned short*)((char*)lV + vo) = vv.us[i];
            }
        }
        __syncthreads();

        // --- QK^T ---
        f32x4 sacc[4] = {};
#pragma unroll
        for (int f = 0; f < 4; ++f) {
            int t = f * 16 + lrow;
            int sw = (t & 7) << 4;
            int ob0 = t * 128 + lgrp * 16;
#pragma unroll
            for (int c = 0; c < 2; ++c) {
                bf16x8 kf = *(const bf16x8*)((const char*)lK + ((ob0 + c * 64) ^ sw));
                sacc[f] = __builtin_amdgcn_mfma_f32_16x16x32_bf16(
                    qf[c], kf, sacc[f], 0, 0, 0);
            }
        }

        // --- mask + row max ---
        float mt[4];
#pragma unroll
        for (int r = 0; r < 4; ++r) mt[r] = -1e30f;
#pragma unroll
        for (int f = 0; f < 4; ++f) {
            int tg = t0 + f * 16 + lrow;
#pragma unroll
            for (int r = 0; r < 4; ++r) {
                int qg = qr0 + lgrp * 4 + r;
                float s = sacc[f][r];
                s = (tg <= qg) ? s : -1e30f;
                sacc[f][r] = s;
                mt[r] = fmaxf(mt[r], s);
            }
        }
#pragma unroll
        for (int msk = 1; msk < 16; msk <<= 1)
#pragma unroll
            for (int r = 0; r < 4; ++r)
                mt[r] = fmaxf(mt[r], __shfl_xor(mt[r], msk, 64));

        float scale[4], psum[4];
#pragma unroll
        for (int r = 0; r < 4; ++r) {
            float mn = fmaxf(m[r], mt[r]);
            scale[r] = __expf(m[r] - mn);
            m[r] = mn;
            psum[r] = 0.f;
        }

        // --- P = exp(s - m), write to per-wave LDS (swizzled) ---
#pragma unroll
        for (int f = 0; f < 4; ++f) {
#pragma unroll
            for (int r = 0; r < 4; ++r) {
                float p = __expf(sacc[f][r] - m[r]);
                psum[r] += p;
                int row = lgrp * 4 + r;
                int t = f * 16 + lrow;
                int po = (row * 128 + t * 2) ^ ((row & 7) << 4);
                *(unsigned short*)((char*)Pw + po) = f2bf(p);
            }
        }
#pragma unroll
        for (int msk = 1; msk < 16; msk <<= 1)
#pragma unroll
            for (int r = 0; r < 4; ++r)
                psum[r] += __shfl_xor(psum[r], msk, 64);
#pragma unroll
        for (int r = 0; r < 4; ++r) l[r] = l[r] * scale[r] + psum[r];
#pragma unroll
        for (int fd = 0; fd < 4; ++fd)
#pragma unroll
            for (int r = 0; r < 4; ++r) oacc[fd][r] *= scale[r];

        // --- PV ---
#pragma unroll
        for (int tc = 0; tc < 2; ++tc) {
            int po = (lrow * 128 + tc * 64 + lgrp * 16) ^ ((lrow & 7) << 4);
            bf16x8 pf = *(const bf16x8*)((const char*)Pw + po);
#pragma unroll
            for (int fd = 0; fd < 4; ++fd) {
                int d = fd * 16 + lrow;
                int vo = (d * 128 + tc * 64 + lgrp * 16) ^ ((d & 7) << 4);
                bf16x8 vf = *(const bf16x8*)((const char*)lV + vo);
                oacc[fd] = __builtin_amdgcn_mfma_f32_16x16x32_bf16(
                    pf, vf, oacc[fd], 0, 0, 0);
            }
        }
    }

    // --- epilogue ---
    const int b = bh >> 4, h = bh & 15;
#pragma unroll
    for (int r = 0; r < 4; ++r) {
        float inv = 1.f / l[r];
        int qg = qr0 + lgrp * 4 + r;
        unsigned short* orow = ob + ((long)b * 2048 + qg) * 1024 + h * 64;
#pragma unroll
        for (int fd = 0; fd < 4; ++fd)
            orow[fd * 16 + lrow] = f2bf(oacc[fd][r] * inv);
    }
}

// ---------------------------------------------------------------------------
extern "C" void kernel_launch(void* const* d_in, const int* in_sizes, int n_in,
                              void* d_out, int out_size, void* d_ws, size_t ws_size,
                              hipStream_t stream) {
    const float* x_in = (const float*)d_in[0];
    const float* Wi   = (const float*)d_in[1];
    const float* cw   = (const float*)d_in[2];
    const float* cb   = (const float*)d_in[3];
    const float* Wo   = (const float*)d_in[4];
    const float* lng  = (const float*)d_in[5];
    const float* lnb  = (const float*)d_in[6];
    const float* wq   = (const float*)d_in[7];
    const float* wk   = (const float*)d_in[8];
    const float* wv   = (const float*)d_in[9];
    const float* wo   = (const float*)d_in[10];
    const float* alng = (const float*)d_in[11];
    const float* alnb = (const float*)d_in[12];
    float* out = (float*)d_out;

    char* ws = (char*)d_ws;
    size_t off = 0;
    auto alloc = [&](size_t bytes) -> void* {
        void* p = ws + off; off += (bytes + 255) & ~(size_t)255; return p;
    };
    unsigned short* xb    = (unsigned short*)alloc(4096ull * 1024 * 2);
    float*          x     = (float*)         alloc(4096ull * 1024 * 4);
    float*          proj  = (float*)         alloc(4096ull * 3072 * 4); // also qkv
    float*          u     = (float*)         alloc(4096ull * 2048 * 4);
    float*          G     = (float*)         alloc(4096ull * 32 * 4);
    unsigned short* yb    = (unsigned short*)alloc(4096ull * 2048 * 2); // also ob
    float*          tmp   = (float*)         alloc(4096ull * 1024 * 4);
    unsigned short* WiT   = (unsigned short*)alloc(5ull * 2176 * 1024 * 2);
    unsigned short* WoT   = (unsigned short*)alloc(5ull * 1024 * 2048 * 2);
    unsigned short* WqkvT = (unsigned short*)alloc(3072ull * 1024 * 2);
    unsigned short* WoaT  = (unsigned short*)alloc(1024ull * 1024 * 2);
    // qkvb (bf16, 25.2 MB) aliases u (fp32, 33.5 MB): u is dead during attn
    unsigned short* qkvb  = (unsigned short*)u;

    // ---- weight prep ----
    transW<<<dim3(34, 16, 5), 256, 0, stream>>>(Wi, WiT, 1024, 2176,
        1024l * 2176, 2176l * 1024);
    transW<<<dim3(16, 32, 5), 256, 0, stream>>>(Wo, WoT, 2048, 1024,
        2048l * 1024, 1024l * 2048);
    transW<<<dim3(16, 16, 1), 256, 0, stream>>>(wq, WqkvT,              1024, 1024, 0, 0);
    transW<<<dim3(16, 16, 1), 256, 0, stream>>>(wk, WqkvT + 1024l*1024, 1024, 1024, 0, 0);
    transW<<<dim3(16, 16, 1), 256, 0, stream>>>(wv, WqkvT + 2048l*1024, 1024, 1024, 0, 0);
    transW<<<dim3(16, 16, 1), 256, 0, stream>>>(wo, WoaT,               1024, 1024, 0, 0);

    init_x<<<4096, 256, 0, stream>>>(x_in, x, xb);

    // ---- 5 SSM layers ----
    for (int j = 0; j < 5; ++j) {
        gemm_bf16<<<dim3(32, 17), 256, 0, stream>>>(
            xb, WiT + (long)j * 2176 * 1024, proj, 4096, 2176, 1024);
        conv_silu<<<8192, 256, 0, stream>>>(
            proj, cw + (long)j * 2048 * 4, cb + (long)j * 2048, u);
        gker<<<1024, 256, 0, stream>>>(proj, G);
        banded<<<dim3(256, 32), 256, 0, stream>>>(G, u, yb);
        gemm_bf16<<<dim3(32, 8), 256, 0, stream>>>(
            yb, WoT + (long)j * 1024 * 2048, tmp, 4096, 1024, 2048);
        ln_fuse<<<4096, 256, 0, stream>>>(
            tmp, x, lng + j * 1024, lnb + j * 1024, x, xb);
    }

    // ---- attention layer ----
    gemm_bf16<<<dim3(32, 24), 256, 0, stream>>>(xb, WqkvT, proj, 4096, 3072, 1024);
    qkv_split<<<12288, 256, 0, stream>>>(proj, qkvb);
    attn_mfma<<<dim3(32, 32), 256, 0, stream>>>(qkvb, yb);
    gemm_bf16<<<dim3(32, 8), 256, 0, stream>>>(yb, WoaT, tmp, 4096, 1024, 1024);
    ln_fuse<<<4096, 256, 0, stream>>>(tmp, x, alng, alnb, out, xb);
}

// Round 5
// 949.310 us; speedup vs baseline: 2.9155x; 1.3064x over previous
//
#include <hip/hip_runtime.h>

typedef __attribute__((ext_vector_type(4))) float v4f;
typedef __attribute__((ext_vector_type(4))) float f32x4;
typedef __attribute__((ext_vector_type(8))) __bf16 bf16x8;
typedef __attribute__((ext_vector_type(4))) unsigned short v4u16;

__device__ __forceinline__ unsigned short f2bf(float f) {
    union { float f; unsigned u; } v; v.f = f;
    unsigned r = v.u + 0x7fffu + ((v.u >> 16) & 1u);
    return (unsigned short)(r >> 16);
}
__device__ __forceinline__ float bf2f(unsigned short s) {
    union { unsigned u; float f; } v; v.u = ((unsigned)s) << 16;
    return v.f;
}

#define GLDS16(gp, lp) __builtin_amdgcn_global_load_lds( \
    (const __attribute__((address_space(1))) void*)(gp), \
    (__attribute__((address_space(3))) void*)(lp), 16, 0, 0)

// ---------------------------------------------------------------------------
// GEMM: C = A[M][K](bf16) * Bt[N][K]^T(bf16).  128x128 tile, BK=32, 4 waves.
// MODE 0: fp32 row-major C.  MODE 1: bf16 row-major C.
// MODE 2: bf16 qkv layout [3][32][2048][64], q scaled by 0.125.
// ---------------------------------------------------------------------------
template <int MODE>
__global__ __launch_bounds__(256) void gemm_bf16(
    const unsigned short* __restrict__ A,
    const unsigned short* __restrict__ Bt,
    void* __restrict__ Cout,
    int M, int N, int K)
{
    __shared__ __align__(16) unsigned short lA[4096];
    __shared__ __align__(16) unsigned short lB[4096];
    const int tid  = threadIdx.x;
    const int wave = tid >> 6;
    const int lane = tid & 63;
    const int wr = wave >> 1, wc = wave & 1;
    const long m0 = (long)blockIdx.x * 128, n0 = (long)blockIdx.y * 128;

    const int srow = tid >> 2;
    const int scol = (tid & 3) * 8;
    const unsigned short* gA0 = A  + (m0 + srow) * (long)K + scol;
    const unsigned short* gB0 = Bt + (n0 + srow) * (long)K + scol;
    const long rstride = 64l * K;
    unsigned short* lA0 = lA + wave * 512;
    unsigned short* lB0 = lB + wave * 512;

    const int fr = lane & 15;
    const int kg = (lane >> 4) * 8;
    const int arow = (wr * 64 + fr) * 32 + kg;
    const int brow = (wc * 64 + fr) * 32 + kg;

    f32x4 acc[4][4] = {};

    for (int k0 = 0; k0 < K; k0 += 32) {
        __syncthreads();
        GLDS16(gA0 + k0,           lA0);
        GLDS16(gA0 + k0 + rstride, lA0 + 2048);
        GLDS16(gB0 + k0,           lB0);
        GLDS16(gB0 + k0 + rstride, lB0 + 2048);
        __syncthreads();
        bf16x8 af[4], bb[4];
#pragma unroll
        for (int m = 0; m < 4; ++m)
            af[m] = *(const bf16x8*)(lA + arow + m * 512);
#pragma unroll
        for (int n = 0; n < 4; ++n)
            bb[n] = *(const bf16x8*)(lB + brow + n * 512);
#pragma unroll
        for (int m = 0; m < 4; ++m)
#pragma unroll
            for (int n = 0; n < 4; ++n)
                acc[m][n] = __builtin_amdgcn_mfma_f32_16x16x32_bf16(
                    af[m], bb[n], acc[m][n], 0, 0, 0);
    }

    const int lgrp = lane >> 4;
    if constexpr (MODE == 0) {
        float* C = (float*)Cout;
        float* Cbase = C + (m0 + wr * 64 + lgrp * 4) * (long)N
                         + n0 + wc * 64 + fr;
#pragma unroll
        for (int m = 0; m < 4; ++m)
#pragma unroll
            for (int n = 0; n < 4; ++n) {
                float* cp = Cbase + m * 16 * (long)N + n * 16;
#pragma unroll
                for (int r = 0; r < 4; ++r)
                    cp[r * (long)N] = acc[m][n][r];
            }
    } else if constexpr (MODE == 1) {
        unsigned short* C = (unsigned short*)Cout;
        unsigned short* Cbase = C + (m0 + wr * 64 + lgrp * 4) * (long)N
                                  + n0 + wc * 64 + fr;
#pragma unroll
        for (int m = 0; m < 4; ++m)
#pragma unroll
            for (int n = 0; n < 4; ++n) {
                unsigned short* cp = Cbase + m * 16 * (long)N + n * 16;
#pragma unroll
                for (int r = 0; r < 4; ++r)
                    cp[r * (long)N] = f2bf(acc[m][n][r]);
            }
    } else {
        // qkv layout: out[((s*32 + b*16 + h)*2048 + t)*64 + d]
        unsigned short* C = (unsigned short*)Cout;
#pragma unroll
        for (int n = 0; n < 4; ++n) {
            int col = (int)n0 + wc * 64 + n * 16 + fr;
            int hb = col >> 6;            // s*16 + h
            int s = hb >> 4, h = hb & 15;
            int d = (n & 3) * 16 + fr;
            float sc = (s == 0) ? 0.125f : 1.f;
            long obase = ((long)(s * 32) + h) * 2048 * 64 + d;
#pragma unroll
            for (int m = 0; m < 4; ++m) {
#pragma unroll
                for (int r = 0; r < 4; ++r) {
                    int row = (int)m0 + wr * 64 + lgrp * 4 + m * 16 + r;
                    int b = row >> 11, t = row & 2047;
                    C[obase + ((long)b * 16 * 2048 + t) * 64] =
                        f2bf(acc[m][n][r] * sc);
                }
            }
        }
    }
}

// ---------------------------------------------------------------------------
// Weight prep: transpose [K][N] fp32 -> [N][K] bf16 (64x64 LDS tiles)
// ---------------------------------------------------------------------------
__global__ __launch_bounds__(256) void transW(
    const float* __restrict__ in, unsigned short* __restrict__ outp,
    int K, int N, long inl, long outl)
{
    __shared__ unsigned short tile[64][65];
    const float* ip = in + (long)blockIdx.z * inl;
    unsigned short* op = outp + (long)blockIdx.z * outl;
    int n0 = blockIdx.x * 64, k0 = blockIdx.y * 64;
    int cc = threadIdx.x & 63, rr = threadIdx.x >> 6;
#pragma unroll
    for (int i = 0; i < 16; ++i) {
        int r = i * 4 + rr;
        tile[r][cc] = f2bf(ip[(long)(k0 + r) * N + n0 + cc]);
    }
    __syncthreads();
#pragma unroll
    for (int i = 0; i < 16; ++i) {
        int r = i * 4 + rr;
        op[(long)(n0 + r) * K + k0 + cc] = tile[cc][r];
    }
}

// x_in -> x (fp32 residual) + xb (bf16)
__global__ __launch_bounds__(256) void init_x(
    const float* __restrict__ xin, float* __restrict__ x,
    unsigned short* __restrict__ xb)
{
    long i = ((long)blockIdx.x * 256 + threadIdx.x) * 4;
    v4f v = *(const v4f*)(xin + i);
    *(v4f*)(x + i) = v;
    v4u16 pk;
#pragma unroll
    for (int j = 0; j < 4; ++j) pk[j] = f2bf(v[j]);
    *(v4u16*)(xb + i) = pk;
}

// ---------------------------------------------------------------------------
// conv_t: depthwise causal conv4 + bias + silu on bf16 proj[:, :2048],
// output TRANSPOSED u_t [2048][4096] bf16.  Block = 64 r x 64 d tile.
// ---------------------------------------------------------------------------
__global__ __launch_bounds__(256) void conv_t(
    const unsigned short* __restrict__ projb,   // [4096][2176] bf16
    const float* __restrict__ cw,               // [2048][4]
    const float* __restrict__ cb,               // [2048]
    unsigned short* __restrict__ ut)            // [2048][4096] bf16
{
    __shared__ unsigned short tile[68][68];     // rows r0-3..r0+63, pad->68
    const int tid = threadIdx.x;
    const int r0 = blockIdx.x * 64, d0 = blockIdx.y * 64;

    for (int idx = tid; idx < 1072; idx += 256) {   // 67 rows x 16 chunks
        int row = idx >> 4, c4 = (idx & 15) * 4;
        int gr = r0 - 3 + row;
        ushort4 v;
        if (gr >= 0) v = *(const ushort4*)(projb + (long)gr * 2176 + d0 + c4);
        else         v = (ushort4){0, 0, 0, 0};
        *(ushort4*)(&tile[row][c4]) = v;
    }
    __syncthreads();

    const int lane = tid & 63;          // r within tile
    const int wave = tid >> 6;
    const int t = (r0 + lane) & 2047;
#pragma unroll
    for (int dd = 0; dd < 16; ++dd) {
        int d = wave * 16 + dd;
        int dch = d0 + d;
        v4f w = *(const v4f*)(cw + (long)dch * 4);
        float a = cb[dch];
#pragma unroll
        for (int kk = 0; kk < 4; ++kk) {
            float xv = (t - 3 + kk >= 0) ? bf2f(tile[lane + kk][d]) : 0.f;
            a += xv * w[kk];
        }
        float sv = a / (1.f + __expf(-a));
        ut[(long)dch * 4096 + r0 + lane] = f2bf(sv);
    }
}

// ---------------------------------------------------------------------------
// band_ssm: y[r][d] = sum_{k=0..31,k<=t} (-0.5)^k (C_r . B_{r-k}) u[r-k][d]
// Block = 32 q-rows x 256 d-cols. 4 waves: wave = c-tile for S, d-chunk for PV.
// ---------------------------------------------------------------------------
__global__ __launch_bounds__(256) void band_ssm(
    const unsigned short* __restrict__ projb,  // [4096][2176] bf16
    const unsigned short* __restrict__ ut,     // [2048][4096] bf16
    unsigned short* __restrict__ yb)           // [4096][2048] bf16
{
    __shared__ __align__(16) unsigned short lU[16384]; // [256 d][64 c] swz
    __shared__ __align__(16) unsigned short lB[4096];  // [64 c][64 s] swz
    __shared__ __align__(16) unsigned short lC[2048];  // [32 i][64 s] swz
    __shared__ __align__(16) unsigned short lP[2048];  // [32 i][64 c] swz

    const int tid = threadIdx.x;
    const int wave = tid >> 6, lane = tid & 63;
    const int r0 = blockIdx.x * 32;
    const int d0 = blockIdx.y * 256;
    const int wb = r0 - 32;

    // ---- stage U^T rows (d), cols c -> r = wb+c ----
#pragma unroll
    for (int p = 0; p < 8; ++p) {
        int chunk = p * 256 + tid;
        int dd = chunk >> 3, j = chunk & 7;
        int off = wb + j * 8; if (off < 0) off = 0;   // masked region, finite
        uint4 v = *(const uint4*)(ut + (long)(d0 + dd) * 4096 + off);
        *(uint4*)((char*)lU + ((dd * 128 + j * 16) ^ ((dd & 7) << 4))) = v;
    }
    // ---- stage B window rows c ----
#pragma unroll
    for (int p = 0; p < 2; ++p) {
        int chunk = p * 256 + tid;
        int c = chunk >> 3, j = chunk & 7;
        int rc = wb + c; if (rc < 0) rc = 0;
        uint4 v = *(const uint4*)(projb + (long)rc * 2176 + 2048 + j * 8);
        *(uint4*)((char*)lB + ((c * 128 + j * 16) ^ ((c & 7) << 4))) = v;
    }
    // ---- stage C tile rows i ----
    {
        int i = tid >> 3, j = tid & 7;
        uint4 v = *(const uint4*)(projb + (long)(r0 + i) * 2176 + 2112 + j * 8);
        *(uint4*)((char*)lC + ((i * 128 + j * 16) ^ ((i & 7) << 4))) = v;
    }
    __syncthreads();

    const int lrow = lane & 15, lgrp = lane >> 4;
    const int sw = (lrow & 7) << 4;

    // ---- S = C @ B^T, this wave's c-tile ----
    {
        f32x4 s[2] = {};
        int cb_ = wave * 16 + lrow;
        bf16x8 b0 = *(const bf16x8*)((const char*)lB + ((cb_ * 128 + lgrp * 16) ^ sw));
        bf16x8 b1 = *(const bf16x8*)((const char*)lB + ((cb_ * 128 + 64 + lgrp * 16) ^ sw));
#pragma unroll
        for (int ti = 0; ti < 2; ++ti) {
            int ar = ti * 16 + lrow;
            bf16x8 a0 = *(const bf16x8*)((const char*)lC + ((ar * 128 + lgrp * 16) ^ sw));
            bf16x8 a1 = *(const bf16x8*)((const char*)lC + ((ar * 128 + 64 + lgrp * 16) ^ sw));
            s[ti] = __builtin_amdgcn_mfma_f32_16x16x32_bf16(a0, b0, s[ti], 0, 0, 0);
            s[ti] = __builtin_amdgcn_mfma_f32_16x16x32_bf16(a1, b1, s[ti], 0, 0, 0);
        }
        // decay + mask -> P (exact 0 outside band/causal)
#pragma unroll
        for (int ti = 0; ti < 2; ++ti) {
#pragma unroll
            for (int r = 0; r < 4; ++r) {
                int i = ti * 16 + lgrp * 4 + r;
                int c = wave * 16 + lrow;
                int k = i + 32 - c;
                int t = (r0 + i) & 2047;
                float p = 0.f;
                if (k >= 0 && k <= 31 && k <= t) {
                    float f = exp2f(-(float)k);
                    p = s[ti][r] * ((k & 1) ? -f : f);
                }
                *(unsigned short*)((char*)lP + ((i * 128 + c * 2) ^ ((i & 7) << 4)))
                    = f2bf(p);
            }
        }
    }
    __syncthreads();

    // ---- Y = P @ U, this wave's 64-col d-chunk ----
    {
        bf16x8 pa[2][2];
#pragma unroll
        for (int ti = 0; ti < 2; ++ti) {
            int pr = ti * 16 + lrow;
            pa[ti][0] = *(const bf16x8*)((const char*)lP + ((pr * 128 + lgrp * 16) ^ sw));
            pa[ti][1] = *(const bf16x8*)((const char*)lP + ((pr * 128 + 64 + lgrp * 16) ^ sw));
        }
#pragma unroll
        for (int dt = 0; dt < 4; ++dt) {
            int dd = wave * 64 + dt * 16 + lrow;
            bf16x8 u0 = *(const bf16x8*)((const char*)lU + ((dd * 128 + lgrp * 16) ^ sw));
            bf16x8 u1 = *(const bf16x8*)((const char*)lU + ((dd * 128 + 64 + lgrp * 16) ^ sw));
#pragma unroll
            for (int ti = 0; ti < 2; ++ti) {
                f32x4 acc = {};
                acc = __builtin_amdgcn_mfma_f32_16x16x32_bf16(pa[ti][0], u0, acc, 0, 0, 0);
                acc = __builtin_amdgcn_mfma_f32_16x16x32_bf16(pa[ti][1], u1, acc, 0, 0, 0);
#pragma unroll
                for (int r = 0; r < 4; ++r) {
                    int i = ti * 16 + lgrp * 4 + r;
                    yb[(long)(r0 + i) * 2048 + d0 + wave * 64 + dt * 16 + lrow]
                        = f2bf(acc[r]);
                }
            }
        }
    }
}

// ---------------------------------------------------------------------------
// LayerNorm(tmp + xres) * g + b -> xout (fp32) and xbout (bf16)
// ---------------------------------------------------------------------------
__global__ __launch_bounds__(256) void ln_fuse(
    const float* __restrict__ tmp, const float* __restrict__ xres,
    const float* __restrict__ g, const float* __restrict__ b,
    float* __restrict__ xout, unsigned short* __restrict__ xbout)
{
    int row = blockIdx.x;
    int tid = threadIdx.x;
    v4f tv = *(const v4f*)(tmp  + (long)row * 1024 + tid * 4);
    v4f rv = *(const v4f*)(xres + (long)row * 1024 + tid * 4);
    v4f v = tv + rv;
    float s = v[0] + v[1] + v[2] + v[3];
    float q = v[0]*v[0] + v[1]*v[1] + v[2]*v[2] + v[3]*v[3];
#pragma unroll
    for (int m = 32; m >= 1; m >>= 1) {
        s += __shfl_xor(s, m, 64);
        q += __shfl_xor(q, m, 64);
    }
    __shared__ float ls[4], lq[4];
    int wave = tid >> 6, lane = tid & 63;
    if (lane == 0) { ls[wave] = s; lq[wave] = q; }
    __syncthreads();
    s = ls[0] + ls[1] + ls[2] + ls[3];
    q = lq[0] + lq[1] + lq[2] + lq[3];
    float mean = s * (1.f / 1024.f);
    float var  = q * (1.f / 1024.f) - mean * mean;
    float rstd = rsqrtf(var + 1e-5f);
    v4f gv = *(const v4f*)(g + tid * 4);
    v4f bv = *(const v4f*)(b + tid * 4);
    v4f o;
#pragma unroll
    for (int i = 0; i < 4; ++i) o[i] = (v[i] - mean) * rstd * gv[i] + bv[i];
    *(v4f*)(xout + (long)row * 1024 + tid * 4) = o;
    v4u16 pk;
#pragma unroll
    for (int i = 0; i < 4; ++i) pk[i] = f2bf(o[i]);
    *(v4u16*)(xbout + (long)row * 1024 + tid * 4) = pk;
}

// ---------------------------------------------------------------------------
// MFMA flash attention (input from gemm<2> directly)
// ---------------------------------------------------------------------------
__global__ __launch_bounds__(256) void attn_mfma(
    const unsigned short* __restrict__ qkvb,   // [3][32][2048][64]
    unsigned short* __restrict__ ob)           // [4096][1024]
{
    __shared__ __align__(16) unsigned short lK[4096];
    __shared__ __align__(16) unsigned short lV[4096];   // transposed [d][t]
    __shared__ __align__(16) unsigned short lP[4][1024];

    const int tid  = threadIdx.x;
    const int wave = tid >> 6;
    const int lane = tid & 63;
    const int bh = blockIdx.x;
    const int qt = blockIdx.y;
    const long base = (long)bh * 2048 * 64;
    const unsigned short* Qg = qkvb + base;
    const unsigned short* Kg = qkvb + 32l * 2048 * 64 + base;
    const unsigned short* Vg = qkvb + 64l * 2048 * 64 + base;

    const int qr0  = qt * 64 + wave * 16;
    const int lrow = lane & 15;
    const int lgrp = lane >> 4;

    bf16x8 qf[2];
    {
        const unsigned short* qp = Qg + (long)(qr0 + lrow) * 64 + lgrp * 8;
        qf[0] = *(const bf16x8*)(qp);
        qf[1] = *(const bf16x8*)(qp + 32);
    }

    f32x4 oacc[4] = {};
    float m[4], l[4];
#pragma unroll
    for (int r = 0; r < 4; ++r) { m[r] = -1e30f; l[r] = 0.f; }

    unsigned short* Pw = lP[wave];
    const int srow = tid >> 2;
    const int sq   = tid & 3;

    const int nkv = qt + 1;
    for (int kb = 0; kb < nkv; ++kb) {
        const int t0 = kb * 64;
        __syncthreads();
        {
            const unsigned short* kp = Kg + (long)(t0 + srow) * 64 + sq * 16;
            uint4 k0 = *(const uint4*)(kp);
            uint4 k1 = *(const uint4*)(kp + 8);
            int off = srow * 128 + sq * 32;
            int sw  = (srow & 7) << 4;
            *(uint4*)((char*)lK + ( off        ^ sw)) = k0;
            *(uint4*)((char*)lK + ((off + 16)  ^ sw)) = k1;
            const unsigned short* vp = Vg + (long)(t0 + srow) * 64 + sq * 16;
            union { uint4 u4[2]; unsigned short us[16]; } vv;
            vv.u4[0] = *(const uint4*)(vp);
            vv.u4[1] = *(const uint4*)(vp + 8);
#pragma unroll
            for (int i = 0; i < 16; ++i) {
                int d = sq * 16 + i;
                int vo = (d * 128 + srow * 2) ^ ((d & 7) << 4);
                *(unsigned short*)((char*)lV + vo) = vv.us[i];
            }
        }
        __syncthreads();

        f32x4 sacc[4] = {};
#pragma unroll
        for (int f = 0; f < 4; ++f) {
            int t = f * 16 + lrow;
            int sw = (t & 7) << 4;
            int ob0 = t * 128 + lgrp * 16;
#pragma unroll
            for (int c = 0; c < 2; ++c) {
                bf16x8 kf = *(const bf16x8*)((const char*)lK + ((ob0 + c * 64) ^ sw));
                sacc[f] = __builtin_amdgcn_mfma_f32_16x16x32_bf16(
                    qf[c], kf, sacc[f], 0, 0, 0);
            }
        }

        float mt[4];
#pragma unroll
        for (int r = 0; r < 4; ++r) mt[r] = -1e30f;
#pragma unroll
        for (int f = 0; f < 4; ++f) {
            int tg = t0 + f * 16 + lrow;
#pragma unroll
            for (int r = 0; r < 4; ++r) {
                int qg = qr0 + lgrp * 4 + r;
                float s = sacc[f][r];
                s = (tg <= qg) ? s : -1e30f;
                sacc[f][r] = s;
                mt[r] = fmaxf(mt[r], s);
            }
        }
#pragma unroll
        for (int msk = 1; msk < 16; msk <<= 1)
#pragma unroll
            for (int r = 0; r < 4; ++r)
                mt[r] = fmaxf(mt[r], __shfl_xor(mt[r], msk, 64));

        float scale[4], psum[4];
#pragma unroll
        for (int r = 0; r < 4; ++r) {
            float mn = fmaxf(m[r], mt[r]);
            scale[r] = __expf(m[r] - mn);
            m[r] = mn;
            psum[r] = 0.f;
        }

#pragma unroll
        for (int f = 0; f < 4; ++f) {
#pragma unroll
            for (int r = 0; r < 4; ++r) {
                float p = __expf(sacc[f][r] - m[r]);
                psum[r] += p;
                int row = lgrp * 4 + r;
                int t = f * 16 + lrow;
                int po = (row * 128 + t * 2) ^ ((row & 7) << 4);
                *(unsigned short*)((char*)Pw + po) = f2bf(p);
            }
        }
#pragma unroll
        for (int msk = 1; msk < 16; msk <<= 1)
#pragma unroll
            for (int r = 0; r < 4; ++r)
                psum[r] += __shfl_xor(psum[r], msk, 64);
#pragma unroll
        for (int r = 0; r < 4; ++r) l[r] = l[r] * scale[r] + psum[r];
#pragma unroll
        for (int fd = 0; fd < 4; ++fd)
#pragma unroll
            for (int r = 0; r < 4; ++r) oacc[fd][r] *= scale[r];

#pragma unroll
        for (int tc = 0; tc < 2; ++tc) {
            int po = (lrow * 128 + tc * 64 + lgrp * 16) ^ ((lrow & 7) << 4);
            bf16x8 pf = *(const bf16x8*)((const char*)Pw + po);
#pragma unroll
            for (int fd = 0; fd < 4; ++fd) {
                int d = fd * 16 + lrow;
                int vo = (d * 128 + tc * 64 + lgrp * 16) ^ ((d & 7) << 4);
                bf16x8 vf = *(const bf16x8*)((const char*)lV + vo);
                oacc[fd] = __builtin_amdgcn_mfma_f32_16x16x32_bf16(
                    pf, vf, oacc[fd], 0, 0, 0);
            }
        }
    }

    const int b = bh >> 4, h = bh & 15;
#pragma unroll
    for (int r = 0; r < 4; ++r) {
        float inv = 1.f / l[r];
        int qg = qr0 + lgrp * 4 + r;
        unsigned short* orow = ob + ((long)b * 2048 + qg) * 1024 + h * 64;
#pragma unroll
        for (int fd = 0; fd < 4; ++fd)
            orow[fd * 16 + lrow] = f2bf(oacc[fd][r] * inv);
    }
}

// ---------------------------------------------------------------------------
extern "C" void kernel_launch(void* const* d_in, const int* in_sizes, int n_in,
                              void* d_out, int out_size, void* d_ws, size_t ws_size,
                              hipStream_t stream) {
    const float* x_in = (const float*)d_in[0];
    const float* Wi   = (const float*)d_in[1];
    const float* cw   = (const float*)d_in[2];
    const float* cb   = (const float*)d_in[3];
    const float* Wo   = (const float*)d_in[4];
    const float* lng  = (const float*)d_in[5];
    const float* lnb  = (const float*)d_in[6];
    const float* wq   = (const float*)d_in[7];
    const float* wk   = (const float*)d_in[8];
    const float* wv   = (const float*)d_in[9];
    const float* wo   = (const float*)d_in[10];
    const float* alng = (const float*)d_in[11];
    const float* alnb = (const float*)d_in[12];
    float* out = (float*)d_out;

    char* ws = (char*)d_ws;
    size_t off = 0;
    auto alloc = [&](size_t bytes) -> void* {
        void* p = ws + off; off += (bytes + 255) & ~(size_t)255; return p;
    };
    unsigned short* xb    = (unsigned short*)alloc(4096ull * 1024 * 2);
    float*          x     = (float*)         alloc(4096ull * 1024 * 4);
    unsigned short* projb = (unsigned short*)alloc(4096ull * 2176 * 2);
    unsigned short* ut    = (unsigned short*)alloc(2048ull * 4096 * 2);
    unsigned short* yb    = (unsigned short*)alloc(4096ull * 2048 * 2); // also ob
    float*          tmp   = (float*)         alloc(4096ull * 1024 * 4);
    unsigned short* qkvb  = (unsigned short*)alloc(3ull * 32 * 2048 * 64 * 2);
    unsigned short* WiT   = (unsigned short*)alloc(5ull * 2176 * 1024 * 2);
    unsigned short* WoT   = (unsigned short*)alloc(5ull * 1024 * 2048 * 2);
    unsigned short* WqkvT = (unsigned short*)alloc(3072ull * 1024 * 2);
    unsigned short* WoaT  = (unsigned short*)alloc(1024ull * 1024 * 2);

    // ---- weight prep ----
    transW<<<dim3(34, 16, 5), 256, 0, stream>>>(Wi, WiT, 1024, 2176,
        1024l * 2176, 2176l * 1024);
    transW<<<dim3(16, 32, 5), 256, 0, stream>>>(Wo, WoT, 2048, 1024,
        2048l * 1024, 1024l * 2048);
    transW<<<dim3(16, 16, 1), 256, 0, stream>>>(wq, WqkvT,              1024, 1024, 0, 0);
    transW<<<dim3(16, 16, 1), 256, 0, stream>>>(wk, WqkvT + 1024l*1024, 1024, 1024, 0, 0);
    transW<<<dim3(16, 16, 1), 256, 0, stream>>>(wv, WqkvT + 2048l*1024, 1024, 1024, 0, 0);
    transW<<<dim3(16, 16, 1), 256, 0, stream>>>(wo, WoaT,               1024, 1024, 0, 0);

    init_x<<<4096, 256, 0, stream>>>(x_in, x, xb);

    // ---- 5 SSM layers ----
    for (int j = 0; j < 5; ++j) {
        gemm_bf16<1><<<dim3(32, 17), 256, 0, stream>>>(
            xb, WiT + (long)j * 2176 * 1024, projb, 4096, 2176, 1024);
        conv_t<<<dim3(64, 32), 256, 0, stream>>>(
            projb, cw + (long)j * 2048 * 4, cb + (long)j * 2048, ut);
        band_ssm<<<dim3(128, 8), 256, 0, stream>>>(projb, ut, yb);
        gemm_bf16<0><<<dim3(32, 8), 256, 0, stream>>>(
            yb, WoT + (long)j * 1024 * 2048, tmp, 4096, 1024, 2048);
        ln_fuse<<<4096, 256, 0, stream>>>(
            tmp, x, lng + j * 1024, lnb + j * 1024, x, xb);
    }

    // ---- attention layer ----
    gemm_bf16<2><<<dim3(32, 24), 256, 0, stream>>>(xb, WqkvT, qkvb, 4096, 3072, 1024);
    attn_mfma<<<dim3(32, 32), 256, 0, stream>>>(qkvb, yb);
    gemm_bf16<0><<<dim3(32, 8), 256, 0, stream>>>(yb, WoaT, tmp, 4096, 1024, 1024);
    ln_fuse<<<4096, 256, 0, stream>>>(tmp, x, alng, alnb, out, xb);
}

// Round 7
// 856.309 us; speedup vs baseline: 3.2322x; 1.1086x over previous
//
#include <hip/hip_runtime.h>

typedef __attribute__((ext_vector_type(4))) float v4f;
typedef __attribute__((ext_vector_type(4))) float f32x4;
typedef __attribute__((ext_vector_type(8))) __bf16 bf16x8;
typedef __attribute__((ext_vector_type(4))) unsigned short v4u16;

__device__ __forceinline__ unsigned short f2bf(float f) {
    union { float f; unsigned u; } v; v.f = f;
    unsigned r = v.u + 0x7fffu + ((v.u >> 16) & 1u);
    return (unsigned short)(r >> 16);
}
__device__ __forceinline__ float bf2f(unsigned short s) {
    union { unsigned u; float f; } v; v.u = ((unsigned)s) << 16;
    return v.f;
}

#define GLDS16(gp, lp) __builtin_amdgcn_global_load_lds( \
    (const __attribute__((address_space(1))) void*)(gp), \
    (__attribute__((address_space(3))) void*)(lp), 16, 0, 0)

// ---------------------------------------------------------------------------
// GEMM: C = A[M][*ldk](bf16) * Bt[N][*ldk]^T(bf16). 128x128 tile, BK=32,
// 4 waves. blockIdx.z = split-K slice (offset z*K cols, output slice z).
// MODE 0: fp32 row-major C (+ z*M*N).  MODE 1: bf16 row-major C.
// MODE 2: bf16 qkv layout [3][32][2048][64], q scaled by 0.125*log2(e).
// ---------------------------------------------------------------------------
template <int MODE>
__global__ __launch_bounds__(256) void gemm_bf16(
    const unsigned short* __restrict__ A,
    const unsigned short* __restrict__ Bt,
    void* __restrict__ Cout,
    int M, int N, int K, int ldk)
{
    __shared__ __align__(16) unsigned short lA[4096];
    __shared__ __align__(16) unsigned short lB[4096];
    const int tid  = threadIdx.x;
    const int wave = tid >> 6;
    const int lane = tid & 63;
    const int wr = wave >> 1, wc = wave & 1;
    const long m0 = (long)blockIdx.x * 128, n0 = (long)blockIdx.y * 128;
    const int kz = blockIdx.z;
    const long koff = (long)kz * K;

    const int srow = tid >> 2;
    const int scol = (tid & 3) * 8;
    const unsigned short* gA0 = A  + (m0 + srow) * (long)ldk + koff + scol;
    const unsigned short* gB0 = Bt + (n0 + srow) * (long)ldk + koff + scol;
    const long rstride = 64l * ldk;
    unsigned short* lA0 = lA + wave * 512;
    unsigned short* lB0 = lB + wave * 512;

    const int fr = lane & 15;
    const int kg = (lane >> 4) * 8;
    const int arow = (wr * 64 + fr) * 32 + kg;
    const int brow = (wc * 64 + fr) * 32 + kg;

    f32x4 acc[4][4] = {};

    for (int k0 = 0; k0 < K; k0 += 32) {
        __syncthreads();
        GLDS16(gA0 + k0,           lA0);
        GLDS16(gA0 + k0 + rstride, lA0 + 2048);
        GLDS16(gB0 + k0,           lB0);
        GLDS16(gB0 + k0 + rstride, lB0 + 2048);
        __syncthreads();
        bf16x8 af[4], bb[4];
#pragma unroll
        for (int m = 0; m < 4; ++m)
            af[m] = *(const bf16x8*)(lA + arow + m * 512);
#pragma unroll
        for (int n = 0; n < 4; ++n)
            bb[n] = *(const bf16x8*)(lB + brow + n * 512);
#pragma unroll
        for (int m = 0; m < 4; ++m)
#pragma unroll
            for (int n = 0; n < 4; ++n)
                acc[m][n] = __builtin_amdgcn_mfma_f32_16x16x32_bf16(
                    af[m], bb[n], acc[m][n], 0, 0, 0);
    }

    const int lgrp = lane >> 4;
    if constexpr (MODE == 0) {
        float* C = (float*)Cout + (long)kz * M * (long)N;
        float* Cbase = C + (m0 + wr * 64 + lgrp * 4) * (long)N
                         + n0 + wc * 64 + fr;
#pragma unroll
        for (int m = 0; m < 4; ++m)
#pragma unroll
            for (int n = 0; n < 4; ++n) {
                float* cp = Cbase + m * 16 * (long)N + n * 16;
#pragma unroll
                for (int r = 0; r < 4; ++r)
                    cp[r * (long)N] = acc[m][n][r];
            }
    } else if constexpr (MODE == 1) {
        unsigned short* C = (unsigned short*)Cout;
        unsigned short* Cbase = C + (m0 + wr * 64 + lgrp * 4) * (long)N
                                  + n0 + wc * 64 + fr;
#pragma unroll
        for (int m = 0; m < 4; ++m)
#pragma unroll
            for (int n = 0; n < 4; ++n) {
                unsigned short* cp = Cbase + m * 16 * (long)N + n * 16;
#pragma unroll
                for (int r = 0; r < 4; ++r)
                    cp[r * (long)N] = f2bf(acc[m][n][r]);
            }
    } else {
        // qkv layout: out[((s*32 + b*16 + h)*2048 + t)*64 + d]
        unsigned short* C = (unsigned short*)Cout;
#pragma unroll
        for (int n = 0; n < 4; ++n) {
            int col = (int)n0 + wc * 64 + n * 16 + fr;
            int hb = col >> 6;            // s*16 + h
            int s = hb >> 4, h = hb & 15;
            int d = (n & 3) * 16 + fr;
            float sc = (s == 0) ? 0.125f * 1.44269504f : 1.f;
            long obase = ((long)(s * 32) + h) * 2048 * 64 + d;
#pragma unroll
            for (int m = 0; m < 4; ++m) {
#pragma unroll
                for (int r = 0; r < 4; ++r) {
                    int row = (int)m0 + wr * 64 + lgrp * 4 + m * 16 + r;
                    int b = row >> 11, t = row & 2047;
                    C[obase + ((long)b * 16 * 2048 + t) * 64] =
                        f2bf(acc[m][n][r] * sc);
                }
            }
        }
    }
}

// ---------------------------------------------------------------------------
// Weight prep: transpose [K][N] fp32 -> [N][K] bf16 (64x64 LDS tiles)
// ---------------------------------------------------------------------------
__global__ __launch_bounds__(256) void transW(
    const float* __restrict__ in, unsigned short* __restrict__ outp,
    int K, int N, long inl, long outl)
{
    __shared__ unsigned short tile[64][65];
    const float* ip = in + (long)blockIdx.z * inl;
    unsigned short* op = outp + (long)blockIdx.z * outl;
    int n0 = blockIdx.x * 64, k0 = blockIdx.y * 64;
    int cc = threadIdx.x & 63, rr = threadIdx.x >> 6;
#pragma unroll
    for (int i = 0; i < 16; ++i) {
        int r = i * 4 + rr;
        tile[r][cc] = f2bf(ip[(long)(k0 + r) * N + n0 + cc]);
    }
    __syncthreads();
#pragma unroll
    for (int i = 0; i < 16; ++i) {
        int r = i * 4 + rr;
        op[(long)(n0 + r) * K + k0 + cc] = tile[cc][r];
    }
}

// ---------------------------------------------------------------------------
// transV: qkvb V segment [32][2048][64] -> vtb [32][64][2048] bf16
// ---------------------------------------------------------------------------
__global__ __launch_bounds__(256) void transV(
    const unsigned short* __restrict__ qkvb, unsigned short* __restrict__ vtb)
{
    __shared__ unsigned short tile[64][72];
    const int tid = threadIdx.x;
    const int bh = blockIdx.x, t0 = blockIdx.y * 64;
    const unsigned short* vg = qkvb + 64l * 2048 * 64
                              + (long)bh * 2048 * 64 + (long)t0 * 64;
    const int row = tid >> 2, c0 = (tid & 3) * 16;
#pragma unroll
    for (int i = 0; i < 4; ++i)
        *(v4u16*)(&tile[row][c0 + i * 4]) =
            *(const v4u16*)(vg + row * 64 + c0 + i * 4);
    __syncthreads();
    const int d = tid >> 2, tc = (tid & 3) * 16;
    unsigned short* vo = vtb + (long)bh * 64 * 2048 + (long)d * 2048 + t0 + tc;
#pragma unroll
    for (int i = 0; i < 4; ++i) {
        v4u16 w;
#pragma unroll
        for (int j = 0; j < 4; ++j) w[j] = tile[tc + i * 4 + j][d];
        *(v4u16*)(vo + i * 4) = w;
    }
}

// x_in -> x (fp32 residual) + xb (bf16)
__global__ __launch_bounds__(256) void init_x(
    const float* __restrict__ xin, float* __restrict__ x,
    unsigned short* __restrict__ xb)
{
    long i = ((long)blockIdx.x * 256 + threadIdx.x) * 4;
    v4f v = *(const v4f*)(xin + i);
    *(v4f*)(x + i) = v;
    v4u16 pk;
#pragma unroll
    for (int j = 0; j < 4; ++j) pk[j] = f2bf(v[j]);
    *(v4u16*)(xb + i) = pk;
}

// ---------------------------------------------------------------------------
// conv_t: depthwise causal conv4 + bias + silu on bf16 proj[:, :2048],
// output TRANSPOSED u_t [2048][4096] bf16.  Block = 64 r x 64 d tile.
// ---------------------------------------------------------------------------
__global__ __launch_bounds__(256) void conv_t(
    const unsigned short* __restrict__ projb,   // [4096][2176] bf16
    const float* __restrict__ cw,               // [2048][4]
    const float* __restrict__ cb,               // [2048]
    unsigned short* __restrict__ ut)            // [2048][4096] bf16
{
    __shared__ unsigned short tile[68][68];
    const int tid = threadIdx.x;
    const int r0 = blockIdx.x * 64, d0 = blockIdx.y * 64;

    for (int idx = tid; idx < 1072; idx += 256) {
        int row = idx >> 4, c4 = (idx & 15) * 4;
        int gr = r0 - 3 + row;
        v4u16 v;
        if (gr >= 0) v = *(const v4u16*)(projb + (long)gr * 2176 + d0 + c4);
        else         v = (v4u16){0, 0, 0, 0};
        *(v4u16*)(&tile[row][c4]) = v;
    }
    __syncthreads();

    const int lane = tid & 63;
    const int wave = tid >> 6;
    const int t = (r0 + lane) & 2047;
#pragma unroll
    for (int dd = 0; dd < 16; ++dd) {
        int d = wave * 16 + dd;
        int dch = d0 + d;
        v4f w = *(const v4f*)(cw + (long)dch * 4);
        float a = cb[dch];
#pragma unroll
        for (int kk = 0; kk < 4; ++kk) {
            float xv = (t - 3 + kk >= 0) ? bf2f(tile[lane + kk][d]) : 0.f;
            a += xv * w[kk];
        }
        float sv = a / (1.f + __expf(-a));
        ut[(long)dch * 4096 + r0 + lane] = f2bf(sv);
    }
}

// ---------------------------------------------------------------------------
// band_ssm: y[r][d] = sum_{k=0..31,k<=t} (-0.5)^k (C_r . B_{r-k}) u[r-k][d]
// ---------------------------------------------------------------------------
__global__ __launch_bounds__(256) void band_ssm(
    const unsigned short* __restrict__ projb,  // [4096][2176] bf16
    const unsigned short* __restrict__ ut,     // [2048][4096] bf16
    unsigned short* __restrict__ yb)           // [4096][2048] bf16
{
    __shared__ __align__(16) unsigned short lU[16384];
    __shared__ __align__(16) unsigned short lB[4096];
    __shared__ __align__(16) unsigned short lC[2048];
    __shared__ __align__(16) unsigned short lP[2048];

    const int tid = threadIdx.x;
    const int wave = tid >> 6, lane = tid & 63;
    const int r0 = blockIdx.x * 32;
    const int d0 = blockIdx.y * 256;
    const int wb = r0 - 32;

#pragma unroll
    for (int p = 0; p < 8; ++p) {
        int chunk = p * 256 + tid;
        int dd = chunk >> 3, j = chunk & 7;
        int off = wb + j * 8; if (off < 0) off = 0;
        uint4 v = *(const uint4*)(ut + (long)(d0 + dd) * 4096 + off);
        *(uint4*)((char*)lU + ((dd * 128 + j * 16) ^ ((dd & 7) << 4))) = v;
    }
#pragma unroll
    for (int p = 0; p < 2; ++p) {
        int chunk = p * 256 + tid;
        int c = chunk >> 3, j = chunk & 7;
        int rc = wb + c; if (rc < 0) rc = 0;
        uint4 v = *(const uint4*)(projb + (long)rc * 2176 + 2048 + j * 8);
        *(uint4*)((char*)lB + ((c * 128 + j * 16) ^ ((c & 7) << 4))) = v;
    }
    {
        int i = tid >> 3, j = tid & 7;
        uint4 v = *(const uint4*)(projb + (long)(r0 + i) * 2176 + 2112 + j * 8);
        *(uint4*)((char*)lC + ((i * 128 + j * 16) ^ ((i & 7) << 4))) = v;
    }
    __syncthreads();

    const int lrow = lane & 15, lgrp = lane >> 4;
    const int sw = (lrow & 7) << 4;

    {
        f32x4 s[2] = {};
        int cb_ = wave * 16 + lrow;
        bf16x8 b0 = *(const bf16x8*)((const char*)lB + ((cb_ * 128 + lgrp * 16) ^ sw));
        bf16x8 b1 = *(const bf16x8*)((const char*)lB + ((cb_ * 128 + 64 + lgrp * 16) ^ sw));
#pragma unroll
        for (int ti = 0; ti < 2; ++ti) {
            int ar = ti * 16 + lrow;
            bf16x8 a0 = *(const bf16x8*)((const char*)lC + ((ar * 128 + lgrp * 16) ^ sw));
            bf16x8 a1 = *(const bf16x8*)((const char*)lC + ((ar * 128 + 64 + lgrp * 16) ^ sw));
            s[ti] = __builtin_amdgcn_mfma_f32_16x16x32_bf16(a0, b0, s[ti], 0, 0, 0);
            s[ti] = __builtin_amdgcn_mfma_f32_16x16x32_bf16(a1, b1, s[ti], 0, 0, 0);
        }
#pragma unroll
        for (int ti = 0; ti < 2; ++ti) {
#pragma unroll
            for (int r = 0; r < 4; ++r) {
                int i = ti * 16 + lgrp * 4 + r;
                int c = wave * 16 + lrow;
                int k = i + 32 - c;
                int t = (r0 + i) & 2047;
                float p = 0.f;
                if (k >= 0 && k <= 31 && k <= t) {
                    float f = exp2f(-(float)k);
                    p = s[ti][r] * ((k & 1) ? -f : f);
                }
                *(unsigned short*)((char*)lP + ((i * 128 + c * 2) ^ ((i & 7) << 4)))
                    = f2bf(p);
            }
        }
    }
    __syncthreads();

    {
        bf16x8 pa[2][2];
#pragma unroll
        for (int ti = 0; ti < 2; ++ti) {
            int pr = ti * 16 + lrow;
            pa[ti][0] = *(const bf16x8*)((const char*)lP + ((pr * 128 + lgrp * 16) ^ sw));
            pa[ti][1] = *(const bf16x8*)((const char*)lP + ((pr * 128 + 64 + lgrp * 16) ^ sw));
        }
#pragma unroll
        for (int dt = 0; dt < 4; ++dt) {
            int dd = wave * 64 + dt * 16 + lrow;
            bf16x8 u0 = *(const bf16x8*)((const char*)lU + ((dd * 128 + lgrp * 16) ^ sw));
            bf16x8 u1 = *(const bf16x8*)((const char*)lU + ((dd * 128 + 64 + lgrp * 16) ^ sw));
#pragma unroll
            for (int ti = 0; ti < 2; ++ti) {
                f32x4 acc = {};
                acc = __builtin_amdgcn_mfma_f32_16x16x32_bf16(pa[ti][0], u0, acc, 0, 0, 0);
                acc = __builtin_amdgcn_mfma_f32_16x16x32_bf16(pa[ti][1], u1, acc, 0, 0, 0);
#pragma unroll
                for (int r = 0; r < 4; ++r) {
                    int i = ti * 16 + lgrp * 4 + r;
                    yb[(long)(r0 + i) * 2048 + d0 + wave * 64 + dt * 16 + lrow]
                        = f2bf(acc[r]);
                }
            }
        }
    }
}

// ---------------------------------------------------------------------------
// LayerNorm(t0 + t1 + xres) * g + b -> xout (fp32) and xbout (bf16)
// (t0/t1 are the two split-K halves of the preceding GEMM)
// ---------------------------------------------------------------------------
__global__ __launch_bounds__(256) void ln_fuse(
    const float* __restrict__ tmp0, const float* __restrict__ tmp1,
    const float* __restrict__ xres,
    const float* __restrict__ g, const float* __restrict__ b,
    float* __restrict__ xout, unsigned short* __restrict__ xbout)
{
    int row = blockIdx.x;
    int tid = threadIdx.x;
    v4f t0 = *(const v4f*)(tmp0 + (long)row * 1024 + tid * 4);
    v4f t1 = *(const v4f*)(tmp1 + (long)row * 1024 + tid * 4);
    v4f rv = *(const v4f*)(xres + (long)row * 1024 + tid * 4);
    v4f v = t0 + t1 + rv;
    float s = v[0] + v[1] + v[2] + v[3];
    float q = v[0]*v[0] + v[1]*v[1] + v[2]*v[2] + v[3]*v[3];
#pragma unroll
    for (int m = 32; m >= 1; m >>= 1) {
        s += __shfl_xor(s, m, 64);
        q += __shfl_xor(q, m, 64);
    }
    __shared__ float ls[4], lq[4];
    int wave = tid >> 6, lane = tid & 63;
    if (lane == 0) { ls[wave] = s; lq[wave] = q; }
    __syncthreads();
    s = ls[0] + ls[1] + ls[2] + ls[3];
    q = lq[0] + lq[1] + lq[2] + lq[3];
    float mean = s * (1.f / 1024.f);
    float var  = q * (1.f / 1024.f) - mean * mean;
    float rstd = rsqrtf(var + 1e-5f);
    v4f gv = *(const v4f*)(g + tid * 4);
    v4f bv = *(const v4f*)(b + tid * 4);
    v4f o;
#pragma unroll
    for (int i = 0; i < 4; ++i) o[i] = (v[i] - mean) * rstd * gv[i] + bv[i];
    *(v4f*)(xout + (long)row * 1024 + tid * 4) = o;
    v4u16 pk;
#pragma unroll
    for (int i = 0; i < 4; ++i) pk[i] = f2bf(o[i]);
    *(v4u16*)(xbout + (long)row * 1024 + tid * 4) = pk;
}

// ---------------------------------------------------------------------------
// MFMA flash attention v2: pre-transposed V, GLDS16 staging with
// pre-swizzled global source, double-buffered K/V, unnormalized exp2 softmax
// (q pre-scaled by 0.125*log2 e in gemm<2>).
// ---------------------------------------------------------------------------
__global__ __launch_bounds__(256) void attn_mfma(
    const unsigned short* __restrict__ qkvb,   // [2][32][2048][64] (q,k)
    const unsigned short* __restrict__ vtb,    // [32][64][2048]
    unsigned short* __restrict__ ob)           // [4096][1024]
{
    __shared__ __align__(16) unsigned short lK[2][4096];
    __shared__ __align__(16) unsigned short lV[2][4096];
    __shared__ __align__(16) unsigned short lP[4][1024];

    const int tid  = threadIdx.x;
    const int wave = tid >> 6;
    const int lane = tid & 63;
    const int bh = blockIdx.x;
    const int qt = blockIdx.y;
    const long base = (long)bh * 2048 * 64;
    const unsigned short* Qg = qkvb + base;
    const char* Kc = (const char*)(qkvb + 32l * 2048 * 64 + base);
    const char* Vc = (const char*)(vtb + (long)bh * 64 * 2048);

    const int qr0  = qt * 64 + wave * 16;
    const int lrow = lane & 15;
    const int lgrp = lane >> 4;

    bf16x8 qf[2];
    {
        const unsigned short* qp = Qg + (long)(qr0 + lrow) * 64 + lgrp * 8;
        qf[0] = *(const bf16x8*)(qp);
        qf[1] = *(const bf16x8*)(qp + 32);
    }

    f32x4 oacc[4] = {};
    float l[4] = {0.f, 0.f, 0.f, 0.f};

    // pre-swizzled staging addresses: linear dest o -> swizzled global src
    const int o0  = wave * 1024 + lane * 16;
    const int ta  = o0 >> 7;
    const int cba = (o0 & 127) ^ ((ta & 7) << 4);
    const int o1  = o0 + 4096;
    const int tb  = o1 >> 7;
    const int cbb = (o1 & 127) ^ ((tb & 7) << 4);
    const int ldst = wave * 1024;     // wave-uniform LDS byte base

#define STAGE(kb_, buf_) do { \
    const int t0_ = (kb_) * 64; \
    GLDS16(Kc + (long)(t0_ + ta) * 128 + cba, (char*)lK[buf_] + ldst); \
    GLDS16(Kc + (long)(t0_ + tb) * 128 + cbb, (char*)lK[buf_] + 4096 + ldst); \
    GLDS16(Vc + (long)ta * 4096 + t0_ * 2 + cba, (char*)lV[buf_] + ldst); \
    GLDS16(Vc + (long)tb * 4096 + t0_ * 2 + cbb, (char*)lV[buf_] + 4096 + ldst); \
} while (0)

    unsigned short* Pw = lP[wave];
    const int nkv = qt + 1;
    STAGE(0, 0);

    for (int kb = 0; kb < nkv; ++kb) {
        const int cur = kb & 1;
        const int t0 = kb * 64;
        __syncthreads();                       // drains in-flight stage
        if (kb + 1 < nkv) STAGE(kb + 1, cur ^ 1);

        // --- QK^T ---
        f32x4 sacc[4] = {};
#pragma unroll
        for (int f = 0; f < 4; ++f) {
            int t = f * 16 + lrow;
            int sw = (t & 7) << 4;
            int ob0 = t * 128 + lgrp * 16;
#pragma unroll
            for (int c = 0; c < 2; ++c) {
                bf16x8 kf = *(const bf16x8*)((const char*)lK[cur] + ((ob0 + c * 64) ^ sw));
                sacc[f] = __builtin_amdgcn_mfma_f32_16x16x32_bf16(
                    qf[c], kf, sacc[f], 0, 0, 0);
            }
        }

        // --- unnormalized softmax: p = 2^s (q pre-scaled by log2 e) ---
        float ps[4] = {0.f, 0.f, 0.f, 0.f};
#pragma unroll
        for (int f = 0; f < 4; ++f) {
            int tg = t0 + f * 16 + lrow;
            int t = f * 16 + lrow;
#pragma unroll
            for (int r = 0; r < 4; ++r) {
                int qg = qr0 + lgrp * 4 + r;
                float p = (tg <= qg) ? exp2f(sacc[f][r]) : 0.f;
                ps[r] += p;
                int row = lgrp * 4 + r;
                int po = (row * 128 + t * 2) ^ ((row & 7) << 4);
                *(unsigned short*)((char*)Pw + po) = f2bf(p);
            }
        }
#pragma unroll
        for (int msk = 1; msk < 16; msk <<= 1)
#pragma unroll
            for (int r = 0; r < 4; ++r)
                ps[r] += __shfl_xor(ps[r], msk, 64);
#pragma unroll
        for (int r = 0; r < 4; ++r) l[r] += ps[r];

        // --- PV ---
#pragma unroll
        for (int tc = 0; tc < 2; ++tc) {
            int po = (lrow * 128 + tc * 64 + lgrp * 16) ^ ((lrow & 7) << 4);
            bf16x8 pf = *(const bf16x8*)((const char*)Pw + po);
#pragma unroll
            for (int fd = 0; fd < 4; ++fd) {
                int d = fd * 16 + lrow;
                int vo = (d * 128 + tc * 64 + lgrp * 16) ^ ((d & 7) << 4);
                bf16x8 vf = *(const bf16x8*)((const char*)lV[cur] + vo);
                oacc[fd] = __builtin_amdgcn_mfma_f32_16x16x32_bf16(
                    pf, vf, oacc[fd], 0, 0, 0);
            }
        }
    }
#undef STAGE

    const int b = bh >> 4, h = bh & 15;
#pragma unroll
    for (int r = 0; r < 4; ++r) {
        float inv = 1.f / l[r];
        int qg = qr0 + lgrp * 4 + r;
        unsigned short* orow = ob + ((long)b * 2048 + qg) * 1024 + h * 64;
#pragma unroll
        for (int fd = 0; fd < 4; ++fd)
            orow[fd * 16 + lrow] = f2bf(oacc[fd][r] * inv);
    }
}

// ---------------------------------------------------------------------------
extern "C" void kernel_launch(void* const* d_in, const int* in_sizes, int n_in,
                              void* d_out, int out_size, void* d_ws, size_t ws_size,
                              hipStream_t stream) {
    const float* x_in = (const float*)d_in[0];
    const float* Wi   = (const float*)d_in[1];
    const float* cw   = (const float*)d_in[2];
    const float* cb   = (const float*)d_in[3];
    const float* Wo   = (const float*)d_in[4];
    const float* lng  = (const float*)d_in[5];
    const float* lnb  = (const float*)d_in[6];
    const float* wq   = (const float*)d_in[7];
    const float* wk   = (const float*)d_in[8];
    const float* wv   = (const float*)d_in[9];
    const float* wo   = (const float*)d_in[10];
    const float* alng = (const float*)d_in[11];
    const float* alnb = (const float*)d_in[12];
    float* out = (float*)d_out;

    char* ws = (char*)d_ws;
    size_t off = 0;
    auto alloc = [&](size_t bytes) -> void* {
        void* p = ws + off; off += (bytes + 255) & ~(size_t)255; return p;
    };
    unsigned short* xb    = (unsigned short*)alloc(4096ull * 1024 * 2);
    float*          x     = (float*)         alloc(4096ull * 1024 * 4);
    unsigned short* projb = (unsigned short*)alloc(4096ull * 2176 * 2);
    unsigned short* ut    = (unsigned short*)alloc(2048ull * 4096 * 2);
    unsigned short* yb    = (unsigned short*)alloc(4096ull * 2048 * 2); // also ob
    float*          tmp   = (float*)         alloc(2ull * 4096 * 1024 * 4); // split-K halves
    unsigned short* qkvb  = (unsigned short*)alloc(3ull * 32 * 2048 * 64 * 2);
    unsigned short* vtb   = (unsigned short*)alloc(32ull * 64 * 2048 * 2);
    unsigned short* WiT   = (unsigned short*)alloc(5ull * 2176 * 1024 * 2);
    unsigned short* WoT   = (unsigned short*)alloc(5ull * 1024 * 2048 * 2);
    unsigned short* WqkvT = (unsigned short*)alloc(3072ull * 1024 * 2);
    unsigned short* WoaT  = (unsigned short*)alloc(1024ull * 1024 * 2);
    float* tmp0 = tmp;
    float* tmp1 = tmp + 4096ull * 1024;

    // ---- weight prep ----
    transW<<<dim3(34, 16, 5), 256, 0, stream>>>(Wi, WiT, 1024, 2176,
        1024l * 2176, 2176l * 1024);
    transW<<<dim3(16, 32, 5), 256, 0, stream>>>(Wo, WoT, 2048, 1024,
        2048l * 1024, 1024l * 2048);
    transW<<<dim3(16, 16, 1), 256, 0, stream>>>(wq, WqkvT,              1024, 1024, 0, 0);
    transW<<<dim3(16, 16, 1), 256, 0, stream>>>(wk, WqkvT + 1024l*1024, 1024, 1024, 0, 0);
    transW<<<dim3(16, 16, 1), 256, 0, stream>>>(wv, WqkvT + 2048l*1024, 1024, 1024, 0, 0);
    transW<<<dim3(16, 16, 1), 256, 0, stream>>>(wo, WoaT,               1024, 1024, 0, 0);

    init_x<<<4096, 256, 0, stream>>>(x_in, x, xb);

    // ---- 5 SSM layers ----
    for (int j = 0; j < 5; ++j) {
        gemm_bf16<1><<<dim3(32, 17), 256, 0, stream>>>(
            xb, WiT + (long)j * 2176 * 1024, projb, 4096, 2176, 1024, 1024);
        conv_t<<<dim3(64, 32), 256, 0, stream>>>(
            projb, cw + (long)j * 2048 * 4, cb + (long)j * 2048, ut);
        band_ssm<<<dim3(128, 8), 256, 0, stream>>>(projb, ut, yb);
        gemm_bf16<0><<<dim3(32, 8, 2), 256, 0, stream>>>(       // split-K=2
            yb, WoT + (long)j * 1024 * 2048, tmp, 4096, 1024, 1024, 2048);
        ln_fuse<<<4096, 256, 0, stream>>>(
            tmp0, tmp1, x, lng + j * 1024, lnb + j * 1024, x, xb);
    }

    // ---- attention layer ----
    gemm_bf16<2><<<dim3(32, 24), 256, 0, stream>>>(xb, WqkvT, qkvb, 4096, 3072, 1024, 1024);
    transV<<<dim3(32, 32), 256, 0, stream>>>(qkvb, vtb);
    attn_mfma<<<dim3(32, 32), 256, 0, stream>>>(qkvb, vtb, yb);
    gemm_bf16<0><<<dim3(32, 8, 2), 256, 0, stream>>>(           // split-K=2
        yb, WoaT, tmp, 4096, 1024, 512, 1024);
    ln_fuse<<<4096, 256, 0, stream>>>(tmp0, tmp1, x, alng, alnb, out, xb);
}

// Round 8
// 755.106 us; speedup vs baseline: 3.6654x; 1.1340x over previous
//
#include <hip/hip_runtime.h>

typedef __attribute__((ext_vector_type(4))) float v4f;
typedef __attribute__((ext_vector_type(4))) float f32x4;
typedef __attribute__((ext_vector_type(8))) __bf16 bf16x8;
typedef __attribute__((ext_vector_type(4))) unsigned short v4u16;

__device__ __forceinline__ unsigned short f2bf(float f) {
    union { float f; unsigned u; } v; v.f = f;
    unsigned r = v.u + 0x7fffu + ((v.u >> 16) & 1u);
    return (unsigned short)(r >> 16);
}
__device__ __forceinline__ float bf2f(unsigned short s) {
    union { unsigned u; float f; } v; v.u = ((unsigned)s) << 16;
    return v.f;
}

#define GLDS16(gp, lp) __builtin_amdgcn_global_load_lds( \
    (const __attribute__((address_space(1))) void*)(gp), \
    (__attribute__((address_space(3))) void*)(lp), 16, 0, 0)

// ---------------------------------------------------------------------------
// GEMM: C = A[M][*ldk](bf16) * Bt[N][*ldk]^T(bf16). 128x128 tile, BK=64,
// XOR-swizzled LDS (linear GLDS dest + pre-swizzled global src + swizzled
// ds_read). blockIdx.z = split-K slice.
// MODE 0: fp32 row-major C (+ z*M*N).  MODE 1: bf16 row-major C.
// MODE 2: bf16 qkv layout [3][32][2048][64], q scaled by 0.125*log2(e).
// ---------------------------------------------------------------------------
template <int MODE>
__global__ __launch_bounds__(256) void gemm_bf16(
    const unsigned short* __restrict__ A,
    const unsigned short* __restrict__ Bt,
    void* __restrict__ Cout,
    int M, int N, int K, int ldk)
{
    __shared__ __align__(16) unsigned short lA[8192];   // [128 r][64 k] swz
    __shared__ __align__(16) unsigned short lB[8192];
    const int tid  = threadIdx.x;
    const int wave = tid >> 6;
    const int lane = tid & 63;
    const int wr = wave >> 1, wc = wave & 1;
    const long m0 = (long)blockIdx.x * 128, n0 = (long)blockIdx.y * 128;
    const int kz = blockIdx.z;
    const long koff = (long)kz * K;

    // staging: issue i covers LDS bytes i*4096 + wave*1024 + lane*16
    //   -> row = i*32 + wave*8 + (lane>>3), colb = (lane&7)*16 (linear dest)
    // source col pre-swizzled so a swizzled read sees logical data
    const int srow = wave * 8 + (lane >> 3);
    const int scb  = ((lane & 7) * 16) ^ ((srow & 7) << 4);
    const char* gA0 = (const char*)(A  + (m0 + srow) * (long)ldk + koff) + scb;
    const char* gB0 = (const char*)(Bt + (n0 + srow) * (long)ldk + koff) + scb;
    const long rstride = 32l * ldk * 2;            // +32 rows, bytes
    unsigned short* lA0 = lA + wave * 512;         // +i*2048 elems per issue
    unsigned short* lB0 = lB + wave * 512;

    const int fr = lane & 15;
    const int lgrp = lane >> 4;
    const int sw = (fr & 7) << 4;
    const int abase = (wr * 64 + fr) * 128 + lgrp * 16;   // bytes
    const int bbase = (wc * 64 + fr) * 128 + lgrp * 16;

    f32x4 acc[4][4] = {};

    for (int k0 = 0; k0 < K; k0 += 64) {
        __syncthreads();
        const long kb = (long)k0 * 2;
#pragma unroll
        for (int i = 0; i < 4; ++i) {
            GLDS16(gA0 + kb + i * rstride, lA0 + i * 2048);
            GLDS16(gB0 + kb + i * rstride, lB0 + i * 2048);
        }
        __syncthreads();
#pragma unroll
        for (int kk = 0; kk < 2; ++kk) {
            bf16x8 af[4], bb[4];
#pragma unroll
            for (int m = 0; m < 4; ++m)
                af[m] = *(const bf16x8*)((const char*)lA +
                        ((abase + m * 2048 + kk * 64) ^ sw));
#pragma unroll
            for (int n = 0; n < 4; ++n)
                bb[n] = *(const bf16x8*)((const char*)lB +
                        ((bbase + n * 2048 + kk * 64) ^ sw));
#pragma unroll
            for (int m = 0; m < 4; ++m)
#pragma unroll
                for (int n = 0; n < 4; ++n)
                    acc[m][n] = __builtin_amdgcn_mfma_f32_16x16x32_bf16(
                        af[m], bb[n], acc[m][n], 0, 0, 0);
        }
    }

    if constexpr (MODE == 0) {
        float* C = (float*)Cout + (long)kz * M * (long)N;
        float* Cbase = C + (m0 + wr * 64 + lgrp * 4) * (long)N
                         + n0 + wc * 64 + fr;
#pragma unroll
        for (int m = 0; m < 4; ++m)
#pragma unroll
            for (int n = 0; n < 4; ++n) {
                float* cp = Cbase + m * 16 * (long)N + n * 16;
#pragma unroll
                for (int r = 0; r < 4; ++r)
                    cp[r * (long)N] = acc[m][n][r];
            }
    } else if constexpr (MODE == 1) {
        unsigned short* C = (unsigned short*)Cout;
        unsigned short* Cbase = C + (m0 + wr * 64 + lgrp * 4) * (long)N
                                  + n0 + wc * 64 + fr;
#pragma unroll
        for (int m = 0; m < 4; ++m)
#pragma unroll
            for (int n = 0; n < 4; ++n) {
                unsigned short* cp = Cbase + m * 16 * (long)N + n * 16;
#pragma unroll
                for (int r = 0; r < 4; ++r)
                    cp[r * (long)N] = f2bf(acc[m][n][r]);
            }
    } else {
        unsigned short* C = (unsigned short*)Cout;
#pragma unroll
        for (int n = 0; n < 4; ++n) {
            int col = (int)n0 + wc * 64 + n * 16 + fr;
            int hb = col >> 6;
            int s = hb >> 4, h = hb & 15;
            int d = (n & 3) * 16 + fr;
            float sc = (s == 0) ? 0.125f * 1.44269504f : 1.f;
            long obase = ((long)(s * 32) + h) * 2048 * 64 + d;
#pragma unroll
            for (int m = 0; m < 4; ++m) {
#pragma unroll
                for (int r = 0; r < 4; ++r) {
                    int row = (int)m0 + wr * 64 + lgrp * 4 + m * 16 + r;
                    int b = row >> 11, t = row & 2047;
                    C[obase + ((long)b * 16 * 2048 + t) * 64] =
                        f2bf(acc[m][n][r] * sc);
                }
            }
        }
    }
}

// ---------------------------------------------------------------------------
// Weight prep: transpose [K][N] fp32 -> [N][K] bf16 (64x64 LDS tiles)
// ---------------------------------------------------------------------------
__global__ __launch_bounds__(256) void transW(
    const float* __restrict__ in, unsigned short* __restrict__ outp,
    int K, int N, long inl, long outl)
{
    __shared__ unsigned short tile[64][65];
    const float* ip = in + (long)blockIdx.z * inl;
    unsigned short* op = outp + (long)blockIdx.z * outl;
    int n0 = blockIdx.x * 64, k0 = blockIdx.y * 64;
    int cc = threadIdx.x & 63, rr = threadIdx.x >> 6;
#pragma unroll
    for (int i = 0; i < 16; ++i) {
        int r = i * 4 + rr;
        tile[r][cc] = f2bf(ip[(long)(k0 + r) * N + n0 + cc]);
    }
    __syncthreads();
#pragma unroll
    for (int i = 0; i < 16; ++i) {
        int r = i * 4 + rr;
        op[(long)(n0 + r) * K + k0 + cc] = tile[cc][r];
    }
}

// ---------------------------------------------------------------------------
// transV: qkvb V segment [32][2048][64] -> vtb [32][64][2048] bf16
// ---------------------------------------------------------------------------
__global__ __launch_bounds__(256) void transV(
    const unsigned short* __restrict__ qkvb, unsigned short* __restrict__ vtb)
{
    __shared__ unsigned short tile[64][72];
    const int tid = threadIdx.x;
    const int bh = blockIdx.x, t0 = blockIdx.y * 64;
    const unsigned short* vg = qkvb + 64l * 2048 * 64
                              + (long)bh * 2048 * 64 + (long)t0 * 64;
    const int row = tid >> 2, c0 = (tid & 3) * 16;
#pragma unroll
    for (int i = 0; i < 4; ++i)
        *(v4u16*)(&tile[row][c0 + i * 4]) =
            *(const v4u16*)(vg + row * 64 + c0 + i * 4);
    __syncthreads();
    const int d = tid >> 2, tc = (tid & 3) * 16;
    unsigned short* vo = vtb + (long)bh * 64 * 2048 + (long)d * 2048 + t0 + tc;
#pragma unroll
    for (int i = 0; i < 4; ++i) {
        v4u16 w;
#pragma unroll
        for (int j = 0; j < 4; ++j) w[j] = tile[tc + i * 4 + j][d];
        *(v4u16*)(vo + i * 4) = w;
    }
}

// x_in -> x (fp32 residual) + xb (bf16)
__global__ __launch_bounds__(256) void init_x(
    const float* __restrict__ xin, float* __restrict__ x,
    unsigned short* __restrict__ xb)
{
    long i = ((long)blockIdx.x * 256 + threadIdx.x) * 4;
    v4f v = *(const v4f*)(xin + i);
    *(v4f*)(x + i) = v;
    v4u16 pk;
#pragma unroll
    for (int j = 0; j < 4; ++j) pk[j] = f2bf(v[j]);
    *(v4u16*)(xb + i) = pk;
}

// ---------------------------------------------------------------------------
// conv_t: depthwise causal conv4 + bias + silu on bf16 proj[:, :2048],
// output TRANSPOSED u_t [2048][4096] bf16.  Block = 64 r x 64 d tile.
// ---------------------------------------------------------------------------
__global__ __launch_bounds__(256) void conv_t(
    const unsigned short* __restrict__ projb,   // [4096][2176] bf16
    const float* __restrict__ cw,               // [2048][4]
    const float* __restrict__ cb,               // [2048]
    unsigned short* __restrict__ ut)            // [2048][4096] bf16
{
    __shared__ unsigned short tile[68][68];
    const int tid = threadIdx.x;
    const int r0 = blockIdx.x * 64, d0 = blockIdx.y * 64;

    for (int idx = tid; idx < 1072; idx += 256) {
        int row = idx >> 4, c4 = (idx & 15) * 4;
        int gr = r0 - 3 + row;
        v4u16 v;
        if (gr >= 0) v = *(const v4u16*)(projb + (long)gr * 2176 + d0 + c4);
        else         v = (v4u16){0, 0, 0, 0};
        *(v4u16*)(&tile[row][c4]) = v;
    }
    __syncthreads();

    const int lane = tid & 63;
    const int wave = tid >> 6;
    const int t = (r0 + lane) & 2047;
#pragma unroll
    for (int dd = 0; dd < 16; ++dd) {
        int d = wave * 16 + dd;
        int dch = d0 + d;
        v4f w = *(const v4f*)(cw + (long)dch * 4);
        float a = cb[dch];
#pragma unroll
        for (int kk = 0; kk < 4; ++kk) {
            float xv = (t - 3 + kk >= 0) ? bf2f(tile[lane + kk][d]) : 0.f;
            a += xv * w[kk];
        }
        float sv = a / (1.f + __expf(-a));
        ut[(long)dch * 4096 + r0 + lane] = f2bf(sv);
    }
}

// ---------------------------------------------------------------------------
// band_ssm: y[r][d] = sum_{k=0..31,k<=t} (-0.5)^k (C_r . B_{r-k}) u[r-k][d]
// ---------------------------------------------------------------------------
__global__ __launch_bounds__(256) void band_ssm(
    const unsigned short* __restrict__ projb,  // [4096][2176] bf16
    const unsigned short* __restrict__ ut,     // [2048][4096] bf16
    unsigned short* __restrict__ yb)           // [4096][2048] bf16
{
    __shared__ __align__(16) unsigned short lU[16384];
    __shared__ __align__(16) unsigned short lB[4096];
    __shared__ __align__(16) unsigned short lC[2048];
    __shared__ __align__(16) unsigned short lP[2048];

    const int tid = threadIdx.x;
    const int wave = tid >> 6, lane = tid & 63;
    const int r0 = blockIdx.x * 32;
    const int d0 = blockIdx.y * 256;
    const int wb = r0 - 32;

#pragma unroll
    for (int p = 0; p < 8; ++p) {
        int chunk = p * 256 + tid;
        int dd = chunk >> 3, j = chunk & 7;
        int off = wb + j * 8; if (off < 0) off = 0;
        uint4 v = *(const uint4*)(ut + (long)(d0 + dd) * 4096 + off);
        *(uint4*)((char*)lU + ((dd * 128 + j * 16) ^ ((dd & 7) << 4))) = v;
    }
#pragma unroll
    for (int p = 0; p < 2; ++p) {
        int chunk = p * 256 + tid;
        int c = chunk >> 3, j = chunk & 7;
        int rc = wb + c; if (rc < 0) rc = 0;
        uint4 v = *(const uint4*)(projb + (long)rc * 2176 + 2048 + j * 8);
        *(uint4*)((char*)lB + ((c * 128 + j * 16) ^ ((c & 7) << 4))) = v;
    }
    {
        int i = tid >> 3, j = tid & 7;
        uint4 v = *(const uint4*)(projb + (long)(r0 + i) * 2176 + 2112 + j * 8);
        *(uint4*)((char*)lC + ((i * 128 + j * 16) ^ ((i & 7) << 4))) = v;
    }
    __syncthreads();

    const int lrow = lane & 15, lgrp = lane >> 4;
    const int sw = (lrow & 7) << 4;

    {
        f32x4 s[2] = {};
        int cb_ = wave * 16 + lrow;
        bf16x8 b0 = *(const bf16x8*)((const char*)lB + ((cb_ * 128 + lgrp * 16) ^ sw));
        bf16x8 b1 = *(const bf16x8*)((const char*)lB + ((cb_ * 128 + 64 + lgrp * 16) ^ sw));
#pragma unroll
        for (int ti = 0; ti < 2; ++ti) {
            int ar = ti * 16 + lrow;
            bf16x8 a0 = *(const bf16x8*)((const char*)lC + ((ar * 128 + lgrp * 16) ^ sw));
            bf16x8 a1 = *(const bf16x8*)((const char*)lC + ((ar * 128 + 64 + lgrp * 16) ^ sw));
            s[ti] = __builtin_amdgcn_mfma_f32_16x16x32_bf16(a0, b0, s[ti], 0, 0, 0);
            s[ti] = __builtin_amdgcn_mfma_f32_16x16x32_bf16(a1, b1, s[ti], 0, 0, 0);
        }
#pragma unroll
        for (int ti = 0; ti < 2; ++ti) {
#pragma unroll
            for (int r = 0; r < 4; ++r) {
                int i = ti * 16 + lgrp * 4 + r;
                int c = wave * 16 + lrow;
                int k = i + 32 - c;
                int t = (r0 + i) & 2047;
                float p = 0.f;
                if (k >= 0 && k <= 31 && k <= t) {
                    float f = exp2f(-(float)k);
                    p = s[ti][r] * ((k & 1) ? -f : f);
                }
                *(unsigned short*)((char*)lP + ((i * 128 + c * 2) ^ ((i & 7) << 4)))
                    = f2bf(p);
            }
        }
    }
    __syncthreads();

    {
        bf16x8 pa[2][2];
#pragma unroll
        for (int ti = 0; ti < 2; ++ti) {
            int pr = ti * 16 + lrow;
            pa[ti][0] = *(const bf16x8*)((const char*)lP + ((pr * 128 + lgrp * 16) ^ sw));
            pa[ti][1] = *(const bf16x8*)((const char*)lP + ((pr * 128 + 64 + lgrp * 16) ^ sw));
        }
#pragma unroll
        for (int dt = 0; dt < 4; ++dt) {
            int dd = wave * 64 + dt * 16 + lrow;
            bf16x8 u0 = *(const bf16x8*)((const char*)lU + ((dd * 128 + lgrp * 16) ^ sw));
            bf16x8 u1 = *(const bf16x8*)((const char*)lU + ((dd * 128 + 64 + lgrp * 16) ^ sw));
#pragma unroll
            for (int ti = 0; ti < 2; ++ti) {
                f32x4 acc = {};
                acc = __builtin_amdgcn_mfma_f32_16x16x32_bf16(pa[ti][0], u0, acc, 0, 0, 0);
                acc = __builtin_amdgcn_mfma_f32_16x16x32_bf16(pa[ti][1], u1, acc, 0, 0, 0);
#pragma unroll
                for (int r = 0; r < 4; ++r) {
                    int i = ti * 16 + lgrp * 4 + r;
                    yb[(long)(r0 + i) * 2048 + d0 + wave * 64 + dt * 16 + lrow]
                        = f2bf(acc[r]);
                }
            }
        }
    }
}

// ---------------------------------------------------------------------------
// LayerNorm(t0 + t1 + xres) * g + b -> xout (fp32) and xbout (bf16)
// ---------------------------------------------------------------------------
__global__ __launch_bounds__(256) void ln_fuse(
    const float* __restrict__ tmp0, const float* __restrict__ tmp1,
    const float* __restrict__ xres,
    const float* __restrict__ g, const float* __restrict__ b,
    float* __restrict__ xout, unsigned short* __restrict__ xbout)
{
    int row = blockIdx.x;
    int tid = threadIdx.x;
    v4f t0 = *(const v4f*)(tmp0 + (long)row * 1024 + tid * 4);
    v4f t1 = *(const v4f*)(tmp1 + (long)row * 1024 + tid * 4);
    v4f rv = *(const v4f*)(xres + (long)row * 1024 + tid * 4);
    v4f v = t0 + t1 + rv;
    float s = v[0] + v[1] + v[2] + v[3];
    float q = v[0]*v[0] + v[1]*v[1] + v[2]*v[2] + v[3]*v[3];
#pragma unroll
    for (int m = 32; m >= 1; m >>= 1) {
        s += __shfl_xor(s, m, 64);
        q += __shfl_xor(q, m, 64);
    }
    __shared__ float ls[4], lq[4];
    int wave = tid >> 6, lane = tid & 63;
    if (lane == 0) { ls[wave] = s; lq[wave] = q; }
    __syncthreads();
    s = ls[0] + ls[1] + ls[2] + ls[3];
    q = lq[0] + lq[1] + lq[2] + lq[3];
    float mean = s * (1.f / 1024.f);
    float var  = q * (1.f / 1024.f) - mean * mean;
    float rstd = rsqrtf(var + 1e-5f);
    v4f gv = *(const v4f*)(g + tid * 4);
    v4f bv = *(const v4f*)(b + tid * 4);
    v4f o;
#pragma unroll
    for (int i = 0; i < 4; ++i) o[i] = (v[i] - mean) * rstd * gv[i] + bv[i];
    *(v4f*)(xout + (long)row * 1024 + tid * 4) = o;
    v4u16 pk;
#pragma unroll
    for (int i = 0; i < 4; ++i) pk[i] = f2bf(o[i]);
    *(v4u16*)(xbout + (long)row * 1024 + tid * 4) = pk;
}

// ---------------------------------------------------------------------------
// MFMA flash attention v3: paired q-tiles for load balance (block handles
// qt=jj and qt=31-jj -> constant 33 KV iters), GLDS16 pre-swizzled staging,
// double-buffered K/V, unnormalized exp2 softmax, MFMA-ones row-sum.
// ---------------------------------------------------------------------------
__global__ __launch_bounds__(256) void attn_mfma(
    const unsigned short* __restrict__ qkvb,   // [2][32][2048][64] (q,k)
    const unsigned short* __restrict__ vtb,    // [32][64][2048]
    unsigned short* __restrict__ ob)           // [4096][1024]
{
    __shared__ __align__(16) unsigned short lK[2][4096];
    __shared__ __align__(16) unsigned short lV[2][4096];
    __shared__ __align__(16) unsigned short lP[4][1024];

    const int tid  = threadIdx.x;
    const int wave = tid >> 6;
    const int lane = tid & 63;
    const int bh = blockIdx.x;
    const int jj = blockIdx.y;                 // 0..15
    const long base = (long)bh * 2048 * 64;
    const unsigned short* Qg = qkvb + base;
    const char* Kc = (const char*)(qkvb + 32l * 2048 * 64 + base);
    const char* Vc = (const char*)(vtb + (long)bh * 64 * 2048);

    const int lrow = lane & 15;
    const int lgrp = lane >> 4;

    // all-ones bf16 A... B-fragment for row-sum MFMA
    bf16x8 onesf;
    {
        union { unsigned short s[8]; bf16x8 v; } ou;
#pragma unroll
        for (int j = 0; j < 8; ++j) ou.s[j] = 0x3F80;
        onesf = ou.v;
    }

    // pre-swizzled staging addresses
    const int o0  = wave * 1024 + lane * 16;
    const int ta  = o0 >> 7;
    const int cba = (o0 & 127) ^ ((ta & 7) << 4);
    const int o1  = o0 + 4096;
    const int tb  = o1 >> 7;
    const int cbb = (o1 & 127) ^ ((tb & 7) << 4);
    const int ldst = wave * 1024;

#define STAGE(kb_, buf_) do { \
    const int t0_ = (kb_) * 64; \
    GLDS16(Kc + (long)(t0_ + ta) * 128 + cba, (char*)lK[buf_] + ldst); \
    GLDS16(Kc + (long)(t0_ + tb) * 128 + cbb, (char*)lK[buf_] + 4096 + ldst); \
    GLDS16(Vc + (long)ta * 4096 + t0_ * 2 + cba, (char*)lV[buf_] + ldst); \
    GLDS16(Vc + (long)tb * 4096 + t0_ * 2 + cbb, (char*)lV[buf_] + 4096 + ldst); \
} while (0)

    unsigned short* Pw = lP[wave];
    const int b = bh >> 4, h = bh & 15;

    for (int half = 0; half < 2; ++half) {
        const int qt = half ? (31 - jj) : jj;
        const int qr0 = qt * 64 + wave * 16;
        const int nkv = qt + 1;

        bf16x8 qf[2];
        {
            const unsigned short* qp = Qg + (long)(qr0 + lrow) * 64 + lgrp * 8;
            qf[0] = *(const bf16x8*)(qp);
            qf[1] = *(const bf16x8*)(qp + 32);
        }
        f32x4 oacc[4] = {};
        f32x4 lacc = {};

        __syncthreads();            // prior half done with LDS
        STAGE(0, 0);

        for (int kb = 0; kb < nkv; ++kb) {
            const int cur = kb & 1;
            const int t0 = kb * 64;
            __syncthreads();                   // drains in-flight stage
            if (kb + 1 < nkv) STAGE(kb + 1, cur ^ 1);

            // --- QK^T ---
            f32x4 sacc[4] = {};
#pragma unroll
            for (int f = 0; f < 4; ++f) {
                int t = f * 16 + lrow;
                int sw = (t & 7) << 4;
                int ob0 = t * 128 + lgrp * 16;
#pragma unroll
                for (int c = 0; c < 2; ++c) {
                    bf16x8 kf = *(const bf16x8*)((const char*)lK[cur] + ((ob0 + c * 64) ^ sw));
                    sacc[f] = __builtin_amdgcn_mfma_f32_16x16x32_bf16(
                        qf[c], kf, sacc[f], 0, 0, 0);
                }
            }

            // --- p = 2^s, masked; store to per-wave P tile ---
#pragma unroll
            for (int f = 0; f < 4; ++f) {
                int tg = t0 + f * 16 + lrow;
                int t = f * 16 + lrow;
#pragma unroll
                for (int r = 0; r < 4; ++r) {
                    int qg = qr0 + lgrp * 4 + r;
                    float p = (tg <= qg) ? exp2f(sacc[f][r]) : 0.f;
                    int row = lgrp * 4 + r;
                    int po = (row * 128 + t * 2) ^ ((row & 7) << 4);
                    *(unsigned short*)((char*)Pw + po) = f2bf(p);
                }
            }

            // --- PV + row-sum via ones-MFMA ---
#pragma unroll
            for (int tc = 0; tc < 2; ++tc) {
                int po = (lrow * 128 + tc * 64 + lgrp * 16) ^ ((lrow & 7) << 4);
                bf16x8 pf = *(const bf16x8*)((const char*)Pw + po);
                lacc = __builtin_amdgcn_mfma_f32_16x16x32_bf16(
                    pf, onesf, lacc, 0, 0, 0);
#pragma unroll
                for (int fd = 0; fd < 4; ++fd) {
                    int d = fd * 16 + lrow;
                    int vo = (d * 128 + tc * 64 + lgrp * 16) ^ ((d & 7) << 4);
                    bf16x8 vf = *(const bf16x8*)((const char*)lV[cur] + vo);
                    oacc[fd] = __builtin_amdgcn_mfma_f32_16x16x32_bf16(
                        pf, vf, oacc[fd], 0, 0, 0);
                }
            }
        }

        // --- epilogue ---
#pragma unroll
        for (int r = 0; r < 4; ++r) {
            float inv = 1.f / lacc[r];
            int qg = qr0 + lgrp * 4 + r;
            unsigned short* orow = ob + ((long)b * 2048 + qg) * 1024 + h * 64;
#pragma unroll
            for (int fd = 0; fd < 4; ++fd)
                orow[fd * 16 + lrow] = f2bf(oacc[fd][r] * inv);
        }
    }
#undef STAGE
}

// ---------------------------------------------------------------------------
extern "C" void kernel_launch(void* const* d_in, const int* in_sizes, int n_in,
                              void* d_out, int out_size, void* d_ws, size_t ws_size,
                              hipStream_t stream) {
    const float* x_in = (const float*)d_in[0];
    const float* Wi   = (const float*)d_in[1];
    const float* cw   = (const float*)d_in[2];
    const float* cb   = (const float*)d_in[3];
    const float* Wo   = (const float*)d_in[4];
    const float* lng  = (const float*)d_in[5];
    const float* lnb  = (const float*)d_in[6];
    const float* wq   = (const float*)d_in[7];
    const float* wk   = (const float*)d_in[8];
    const float* wv   = (const float*)d_in[9];
    const float* wo   = (const float*)d_in[10];
    const float* alng = (const float*)d_in[11];
    const float* alnb = (const float*)d_in[12];
    float* out = (float*)d_out;

    char* ws = (char*)d_ws;
    size_t off = 0;
    auto alloc = [&](size_t bytes) -> void* {
        void* p = ws + off; off += (bytes + 255) & ~(size_t)255; return p;
    };
    unsigned short* xb    = (unsigned short*)alloc(4096ull * 1024 * 2);
    float*          x     = (float*)         alloc(4096ull * 1024 * 4);
    unsigned short* projb = (unsigned short*)alloc(4096ull * 2176 * 2);
    unsigned short* ut    = (unsigned short*)alloc(2048ull * 4096 * 2);
    unsigned short* yb    = (unsigned short*)alloc(4096ull * 2048 * 2); // also ob
    float*          tmp   = (float*)         alloc(2ull * 4096 * 1024 * 4);
    unsigned short* qkvb  = (unsigned short*)alloc(3ull * 32 * 2048 * 64 * 2);
    unsigned short* vtb   = (unsigned short*)alloc(32ull * 64 * 2048 * 2);
    unsigned short* WiT   = (unsigned short*)alloc(5ull * 2176 * 1024 * 2);
    unsigned short* WoT   = (unsigned short*)alloc(5ull * 1024 * 2048 * 2);
    unsigned short* WqkvT = (unsigned short*)alloc(3072ull * 1024 * 2);
    unsigned short* WoaT  = (unsigned short*)alloc(1024ull * 1024 * 2);
    float* tmp0 = tmp;
    float* tmp1 = tmp + 4096ull * 1024;

    // ---- weight prep ----
    transW<<<dim3(34, 16, 5), 256, 0, stream>>>(Wi, WiT, 1024, 2176,
        1024l * 2176, 2176l * 1024);
    transW<<<dim3(16, 32, 5), 256, 0, stream>>>(Wo, WoT, 2048, 1024,
        2048l * 1024, 1024l * 2048);
    transW<<<dim3(16, 16, 1), 256, 0, stream>>>(wq, WqkvT,              1024, 1024, 0, 0);
    transW<<<dim3(16, 16, 1), 256, 0, stream>>>(wk, WqkvT + 1024l*1024, 1024, 1024, 0, 0);
    transW<<<dim3(16, 16, 1), 256, 0, stream>>>(wv, WqkvT + 2048l*1024, 1024, 1024, 0, 0);
    transW<<<dim3(16, 16, 1), 256, 0, stream>>>(wo, WoaT,               1024, 1024, 0, 0);

    init_x<<<4096, 256, 0, stream>>>(x_in, x, xb);

    // ---- 5 SSM layers ----
    for (int j = 0; j < 5; ++j) {
        gemm_bf16<1><<<dim3(32, 17), 256, 0, stream>>>(
            xb, WiT + (long)j * 2176 * 1024, projb, 4096, 2176, 1024, 1024);
        conv_t<<<dim3(64, 32), 256, 0, stream>>>(
            projb, cw + (long)j * 2048 * 4, cb + (long)j * 2048, ut);
        band_ssm<<<dim3(128, 8), 256, 0, stream>>>(projb, ut, yb);
        gemm_bf16<0><<<dim3(32, 8, 2), 256, 0, stream>>>(       // split-K=2
            yb, WoT + (long)j * 1024 * 2048, tmp, 4096, 1024, 1024, 2048);
        ln_fuse<<<4096, 256, 0, stream>>>(
            tmp0, tmp1, x, lng + j * 1024, lnb + j * 1024, x, xb);
    }

    // ---- attention layer ----
    gemm_bf16<2><<<dim3(32, 24), 256, 0, stream>>>(xb, WqkvT, qkvb, 4096, 3072, 1024, 1024);
    transV<<<dim3(32, 32), 256, 0, stream>>>(qkvb, vtb);
    attn_mfma<<<dim3(32, 16), 256, 0, stream>>>(qkvb, vtb, yb);
    gemm_bf16<0><<<dim3(32, 8, 2), 256, 0, stream>>>(           // split-K=2
        yb, WoaT, tmp, 4096, 1024, 512, 1024);
    ln_fuse<<<4096, 256, 0, stream>>>(tmp0, tmp1, x, alng, alnb, out, xb);
}